// Round 4
// baseline (2357.162 us; speedup 1.0000x reference)
//
#include <hip/hip_runtime.h>
#include <hip/hip_bf16.h>

#define NSN 5000
#define NMN 100000
#define NRN 2000
#define HDIM 128
#define ESM 2000000
#define ERM 1000000
#define ESIM 2000000
#define LBL 500000

#define CNT_TOTAL (4 * NMN + NSN + NRN)  // 407000
#define POOL_TOTAL (2 * ESM + 2 * ERM + 2 * ESIM)  // 10M

typedef short bf16x8 __attribute__((ext_vector_type(8)));
typedef float f32x4 __attribute__((ext_vector_type(4)));

__device__ __forceinline__ unsigned short f2bf(float f) {
  unsigned u = __float_as_uint(f);
  unsigned r = (u + 0x7fffu + ((u >> 16) & 1u)) >> 16;  // RNE
  return (unsigned short)r;
}
__device__ __forceinline__ float bf_lo(unsigned v) { return __uint_as_float(v << 16); }
__device__ __forceinline__ float bf_hi(unsigned v) { return __uint_as_float(v & 0xffff0000u); }
__device__ __forceinline__ unsigned pack2(float x, float y) {
  return (unsigned)f2bf(x) | ((unsigned)f2bf(y) << 16);
}

// ---------------- CSR build ----------------

__global__ void zero_int(int* __restrict__ p, int n) {
  int i = blockIdx.x * blockDim.x + threadIdx.x;
  if (i < n) p[i] = 0;
}

// combined forward+reverse histogram
__global__ void hist2(const int* __restrict__ a, const int* __restrict__ b, int n,
                      int* __restrict__ cntA, int* __restrict__ cntB) {
  int i = blockIdx.x * blockDim.x + threadIdx.x;
  if (i < n) {
    atomicAdd(&cntA[b[i]], 1);  // dst-indexed
    atomicAdd(&cntB[a[i]], 1);  // src-indexed
  }
}

// global 3-phase exclusive scan over the whole cnt buffer (407000 elems)
__global__ void scan_partial(const int* __restrict__ cnt, int n, int* __restrict__ bsum) {
  __shared__ int sdata[256];
  int b = blockIdx.x, t = threadIdx.x;
  int base = b * 1024;
  int s = 0;
  for (int j = t; j < 1024; j += 256) { int i = base + j; if (i < n) s += cnt[i]; }
  sdata[t] = s; __syncthreads();
  for (int o = 128; o > 0; o >>= 1) { if (t < o) sdata[t] += sdata[t + o]; __syncthreads(); }
  if (t == 0) bsum[b] = sdata[0];
}

__global__ void scan_bsum(int* __restrict__ bsum, int nb, int* __restrict__ off_end) {
  __shared__ int buf[512];
  int t = threadIdx.x;  // 512 threads
  int v = (t < nb) ? bsum[t] : 0;
  buf[t] = v; __syncthreads();
  for (int o = 1; o < 512; o <<= 1) {
    int a = (t >= o) ? buf[t - o] : 0;
    __syncthreads();
    buf[t] += a;
    __syncthreads();
  }
  if (t < nb) bsum[t] = buf[t] - v;     // exclusive
  if (t == 511) *off_end = buf[511];    // grand total -> off[CNT_TOTAL]
}

__global__ void scan_write(const int* __restrict__ cnt, int n, const int* __restrict__ bsum,
                           int* __restrict__ off) {
  __shared__ int buf[256];
  int b = blockIdx.x, t = threadIdx.x;
  int base = b * 1024 + t * 4;
  int v0 = 0, v1 = 0, v2 = 0, v3 = 0;
  if (base + 0 < n) v0 = cnt[base + 0];
  if (base + 1 < n) v1 = cnt[base + 1];
  if (base + 2 < n) v2 = cnt[base + 2];
  if (base + 3 < n) v3 = cnt[base + 3];
  int s = v0 + v1 + v2 + v3;
  buf[t] = s; __syncthreads();
  for (int o = 1; o < 256; o <<= 1) {
    int a = (t >= o) ? buf[t - o] : 0;
    __syncthreads();
    buf[t] += a;
    __syncthreads();
  }
  int run = buf[t] - s + bsum[b];
  if (base + 0 < n) off[base + 0] = run; run += v0;
  if (base + 1 < n) off[base + 1] = run; run += v1;
  if (base + 2 < n) off[base + 2] = run; run += v2;
  if (base + 3 < n) off[base + 3] = run;
}

// Region-bucketed combined fwd+rev CSR fill.
// 8 regions; block (c*8+r) scans edge chunk c, performs only scatters whose
// target node falls in region r (fwd: dst/DA, rev: src/DB). With round-robin
// blockIdx%8 -> XCD dispatch, each pool line is written by ONE XCD's L2 and
// accumulates all its stores before a single writeback (kills the 16x write
// amplification seen in R3: WRITE 252MB for 16MB useful). Correct regardless
// of dispatch mapping; XCD affinity is a perf heuristic only.
#define FILL_CH 8192
template <int DA, int DB>
__global__ __launch_bounds__(256) void fillcsr2_rb(
    const int* __restrict__ a, const int* __restrict__ b, int n,
    const int* __restrict__ offA, int* __restrict__ curA,
    const int* __restrict__ offB, int* __restrict__ curB,
    int* __restrict__ pool) {
  int r = blockIdx.x & 7;
  int c = blockIdx.x >> 3;
  int base = c * FILL_CH;
  int end = min(base + FILL_CH, n);
  for (int i = base + (int)threadIdx.x; i < end; i += 256) {
    int s_ = a[i], d = b[i];
    if (d / DA == r) {
      int p_ = atomicAdd(&curA[d], 1);
      pool[offA[d] + p_] = s_;
    }
    if (s_ / DB == r) {
      int q_ = atomicAdd(&curB[s_], 1);
      pool[offB[s_] + q_] = d;
    }
  }
}

__global__ void compute_dinv(const int* __restrict__ off1, const int* __restrict__ off2,
                             float* __restrict__ dinv1, float* __restrict__ dinv2, int n) {
  int v = blockIdx.x * blockDim.x + threadIdx.x;
  if (v < n) {
    dinv1[v] = rsqrtf((float)(off1[v + 1] - off1[v] + 1));
    dinv2[v] = rsqrtf((float)(off2[v + 1] - off2[v] + 1));
  }
}

// bf16 transposed weights wt[(l*9+slot)][n][k], slots:
// 0..3 = sage_Wl rel0..3; 4,5 = gcn_W; 6 = Wr0+Wr2; 7 = Wr1; 8 = Wr3
__global__ void trans_weights(const float* __restrict__ sWl, const float* __restrict__ sWr,
                              const float* __restrict__ gW, unsigned short* __restrict__ wt) {
  int i = blockIdx.x * blockDim.x + threadIdx.x;
  if (i >= 18 * 16384) return;
  int mat = i >> 14, l = mat / 9, slot = mat % 9;
  int idx = i & 16383, nn = idx >> 7, kk = idx & 127;
  int s_ = kk * 128 + nn;  // source [k][n] row-major
  float v;
  if (slot < 4)      v = sWl[((l * 4 + slot) << 14) + s_];
  else if (slot < 6) v = gW[((l * 2 + (slot - 4)) << 14) + s_];
  else if (slot == 6) v = sWr[((l * 4 + 0) << 14) + s_] + sWr[((l * 4 + 2) << 14) + s_];
  else if (slot == 7) v = sWr[((l * 4 + 1) << 14) + s_];
  else                v = sWr[((l * 4 + 3) << 14) + s_];
  wt[i] = f2bf(v);
}

__global__ void prep_bias(const float* __restrict__ sbl, const float* __restrict__ gb,
                          float* __restrict__ biasM) {
  int i = threadIdx.x;  // 256 threads
  int l = i >> 7, j = i & 127;
  biasM[i] = sbl[(l * 4 + 0) * 128 + j] + sbl[(l * 4 + 2) * 128 + j] +
             gb[(l * 2 + 0) * 128 + j] + gb[(l * 2 + 1) * 128 + j];
}

// one merged cast for all three embedding tables
__global__ void cast_all(const float2* __restrict__ es, const float2* __restrict__ em,
                         const float2* __restrict__ er, unsigned* __restrict__ os,
                         unsigned* __restrict__ om, unsigned* __restrict__ orr) {
  int i = blockIdx.x * blockDim.x + threadIdx.x;
  if (i < NSN * 64) {
    float2 v = es[i]; os[i] = pack2(v.x, v.y);
  }
  if (i < NMN * 64) {
    float2 v = em[i]; om[i] = pack2(v.x, v.y);
  }
  if (i < NRN * 64) {
    float2 v = er[i]; orr[i] = pack2(v.x, v.y);
  }
}

// ---------------- aggregation ----------------
// 1 wave per dst node (NM targets, low degree), unroll-4 ILP

__global__ void sage_agg(const unsigned* __restrict__ x, const int* __restrict__ pool,
                         const int* __restrict__ off, unsigned* __restrict__ outb, int n) {
  int w = (blockIdx.x * blockDim.x + threadIdx.x) >> 6;
  if (w >= n) return;
  int lane = threadIdx.x & 63;
  int s = off[w], e = off[w + 1];
  float ax = 0.f, ay = 0.f;
  int i = s;
  for (; i + 3 < e; i += 4) {
    int u0 = pool[i], u1 = pool[i + 1], u2 = pool[i + 2], u3 = pool[i + 3];
    unsigned v0 = x[(size_t)u0 * 64 + lane];
    unsigned v1 = x[(size_t)u1 * 64 + lane];
    unsigned v2 = x[(size_t)u2 * 64 + lane];
    unsigned v3 = x[(size_t)u3 * 64 + lane];
    ax += (bf_lo(v0) + bf_lo(v1)) + (bf_lo(v2) + bf_lo(v3));
    ay += (bf_hi(v0) + bf_hi(v1)) + (bf_hi(v2) + bf_hi(v3));
  }
  for (; i < e; ++i) {
    unsigned v = x[(size_t)pool[i] * 64 + lane];
    ax += bf_lo(v); ay += bf_hi(v);
  }
  float inv = (e > s) ? 1.0f / (float)(e - s) : 0.0f;
  outb[(size_t)w * 64 + lane] = pack2(ax * inv, ay * inv);
}

// 4 waves per dst node (NS/NR targets, high degree), LDS combine
__global__ __launch_bounds__(256) void sage_agg_mw(const unsigned* __restrict__ x,
                                                   const int* __restrict__ pool,
                                                   const int* __restrict__ off,
                                                   unsigned* __restrict__ outb, int n) {
  __shared__ float2 psum[3][64];
  int node = blockIdx.x;
  if (node >= n) return;
  int sub = threadIdx.x >> 6, lane = threadIdx.x & 63;
  int s = off[node], e = off[node + 1];
  float ax = 0.f, ay = 0.f;
  int i = s + sub;
  for (; i + 12 < e; i += 16) {
    int u0 = pool[i], u1 = pool[i + 4], u2 = pool[i + 8], u3 = pool[i + 12];
    unsigned v0 = x[(size_t)u0 * 64 + lane];
    unsigned v1 = x[(size_t)u1 * 64 + lane];
    unsigned v2 = x[(size_t)u2 * 64 + lane];
    unsigned v3 = x[(size_t)u3 * 64 + lane];
    ax += (bf_lo(v0) + bf_lo(v1)) + (bf_lo(v2) + bf_lo(v3));
    ay += (bf_hi(v0) + bf_hi(v1)) + (bf_hi(v2) + bf_hi(v3));
  }
  for (; i < e; i += 4) {
    unsigned v = x[(size_t)pool[i] * 64 + lane];
    ax += bf_lo(v); ay += bf_hi(v);
  }
  if (sub) psum[sub - 1][lane] = make_float2(ax, ay);
  __syncthreads();
  if (sub == 0) {
#pragma unroll
    for (int j = 0; j < 3; j++) {
      float2 t = psum[j][lane];
      ax += t.x; ay += t.y;
    }
    float inv = (e > s) ? 1.0f / (float)(e - s) : 0.0f;
    outb[(size_t)node * 64 + lane] = pack2(ax * inv, ay * inv);
  }
}

__global__ void gcn_agg(const unsigned* __restrict__ x, const int* __restrict__ pool,
                        const int* __restrict__ off, const float* __restrict__ dinv,
                        unsigned* __restrict__ outb, int n) {
  int w = (blockIdx.x * blockDim.x + threadIdx.x) >> 6;
  if (w >= n) return;
  int lane = threadIdx.x & 63;
  int s = off[w], e = off[w + 1];
  float ax = 0.f, ay = 0.f;
  int i = s;
  for (; i + 3 < e; i += 4) {
    int u0 = pool[i], u1 = pool[i + 1], u2 = pool[i + 2], u3 = pool[i + 3];
    float d0 = dinv[u0], d1 = dinv[u1], d2 = dinv[u2], d3 = dinv[u3];
    unsigned v0 = x[(size_t)u0 * 64 + lane];
    unsigned v1 = x[(size_t)u1 * 64 + lane];
    unsigned v2 = x[(size_t)u2 * 64 + lane];
    unsigned v3 = x[(size_t)u3 * 64 + lane];
    ax += bf_lo(v0) * d0 + bf_lo(v1) * d1 + bf_lo(v2) * d2 + bf_lo(v3) * d3;
    ay += bf_hi(v0) * d0 + bf_hi(v1) * d1 + bf_hi(v2) * d2 + bf_hi(v3) * d3;
  }
  for (; i < e; ++i) {
    int u = pool[i];
    float du = dinv[u];
    unsigned v = x[(size_t)u * 64 + lane];
    ax += bf_lo(v) * du; ay += bf_hi(v) * du;
  }
  float dw = dinv[w];
  unsigned xv = x[(size_t)w * 64 + lane];
  outb[(size_t)w * 64 + lane] =
      pack2(ax * dw + bf_lo(xv) * dw * dw, ay * dw + bf_hi(xv) * dw * dw);
}

// ---------------- MFMA GEMM: out = relu(bias + sum_p A_p @ W_p) ----------------

#define LDA 136

__global__ __launch_bounds__(256) void gemm_mfma(
    const unsigned short* __restrict__ a0, const unsigned short* __restrict__ w0,
    const unsigned short* __restrict__ a1, const unsigned short* __restrict__ w1,
    const unsigned short* __restrict__ a2, const unsigned short* __restrict__ w2,
    const unsigned short* __restrict__ a3, const unsigned short* __restrict__ w3,
    const unsigned short* __restrict__ a4, const unsigned short* __restrict__ w4,
    const float* __restrict__ bias, unsigned short* __restrict__ out, int n) {
  __shared__ __align__(16) unsigned short As[64 * LDA];
  __shared__ __align__(16) unsigned short Ws[128 * LDA];

  int tid = threadIdx.x;
  int w = tid >> 6, lane = tid & 63;
  int q = lane >> 4, c = lane & 15;
  int r0 = blockIdx.x * 64;

  const unsigned short* Ap[5] = {a0, a1, a2, a3, a4};
  const unsigned short* Wp[5] = {w0, w1, w2, w3, w4};

  float bias_v[8];
#pragma unroll
  for (int n0 = 0; n0 < 8; n0++) bias_v[n0] = bias[n0 * 16 + c];

  f32x4 acc[8];
#pragma unroll
  for (int n0 = 0; n0 < 8; n0++) acc[n0] = (f32x4){0.f, 0.f, 0.f, 0.f};

  for (int p = 0; p < 5; p++) {
    if (!Ap[p]) continue;
    __syncthreads();
    for (int j = tid; j < 2048; j += 256) {
      int row = j >> 4, colc = (j & 15) * 8;
      *(uint4*)&Ws[row * LDA + colc] = *(const uint4*)(Wp[p] + row * 128 + colc);
    }
    for (int j = tid; j < 1024; j += 256) {
      int row = j >> 4, colc = (j & 15) * 8;
      uint4 v = make_uint4(0u, 0u, 0u, 0u);
      if (r0 + row < n) v = *(const uint4*)(Ap[p] + (size_t)(r0 + row) * 128 + colc);
      *(uint4*)&As[row * LDA + colc] = v;
    }
    __syncthreads();

    int arow = (w * 16 + c) * LDA;
#pragma unroll
    for (int k0 = 0; k0 < 128; k0 += 32) {
      bf16x8 af = *(const bf16x8*)&As[arow + k0 + q * 8];
#pragma unroll
      for (int n0 = 0; n0 < 8; n0++) {
        bf16x8 bfv = *(const bf16x8*)&Ws[(n0 * 16 + c) * LDA + k0 + q * 8];
        acc[n0] = __builtin_amdgcn_mfma_f32_16x16x32_bf16(af, bfv, acc[n0], 0, 0, 0);
      }
    }
  }

  __syncthreads();
#pragma unroll
  for (int n0 = 0; n0 < 8; n0++) {
#pragma unroll
    for (int reg = 0; reg < 4; reg++) {
      float v = acc[n0][reg] + bias_v[n0];
      v = fmaxf(v, 0.f);
      As[(w * 16 + q * 4 + reg) * LDA + n0 * 16 + c] = f2bf(v);
    }
  }
  __syncthreads();
  for (int j = tid; j < 1024; j += 256) {
    int row = j >> 4, colc = (j & 15) * 8;
    if (r0 + row < n)
      *(uint4*)(out + (size_t)(r0 + row) * 128 + colc) = *(const uint4*)&As[row * LDA + colc];
  }
}

// ---------------- final dot products ----------------

__global__ void dots_kernel(const unsigned* __restrict__ xs, const unsigned* __restrict__ xm,
                            const unsigned* __restrict__ xr, const int* __restrict__ ls,
                            const int* __restrict__ lm, const int* __restrict__ lr,
                            float* __restrict__ out) {
  int i = (blockIdx.x * blockDim.x + threadIdx.x) >> 6;
  if (i >= LBL) return;
  int lane = threadIdx.x & 63;
  unsigned mv = xm[(size_t)lm[i] * 64 + lane];
  unsigned sv = xs[(size_t)ls[i] * 64 + lane];
  unsigned rv = xr[(size_t)lr[i] * 64 + lane];
  float mx = bf_lo(mv), my = bf_hi(mv);
  float p1 = bf_lo(sv) * mx + bf_hi(sv) * my;
  float p2 = bf_lo(rv) * mx + bf_hi(rv) * my;
#pragma unroll
  for (int o = 32; o > 0; o >>= 1) {
    p1 += __shfl_down(p1, o, 64);
    p2 += __shfl_down(p2, o, 64);
  }
  if (lane == 0) { out[i] = p1; out[LBL + i] = p2; }
}

// ---------------- host launcher ----------------

extern "C" void kernel_launch(void* const* d_in, const int* in_sizes, int n_in,
                              void* d_out, int out_size, void* d_ws, size_t ws_size,
                              hipStream_t stream) {
  const float* emb_s = (const float*)d_in[0];
  const float* emb_m = (const float*)d_in[1];
  const float* emb_r = (const float*)d_in[2];
  const float* sWl = (const float*)d_in[3];
  const float* sbl = (const float*)d_in[4];
  const float* sWr = (const float*)d_in[5];
  const float* gW  = (const float*)d_in[6];
  const float* gb  = (const float*)d_in[7];
  const int* src_sm  = (const int*)d_in[8];
  const int* dst_sm  = (const int*)d_in[9];
  const int* src_rm  = (const int*)d_in[10];
  const int* dst_rm  = (const int*)d_in[11];
  const int* src_sim = (const int*)d_in[12];
  const int* dst_sim = (const int*)d_in[13];
  const int* lbl_s = (const int*)d_in[14];
  const int* lbl_m = (const int*)d_in[15];
  const int* lbl_r = (const int*)d_in[16];
  float* out = (float*)d_out;

  char* p = (char*)d_ws;
  auto alloc = [&](size_t bytes) -> char* {
    char* r = p;
    p += (bytes + 255) & ~(size_t)255;
    return r;
  };

  // cnt groups in pool order: sm_d(NM), sm_s(NS), rm_d(NM), rm_s(NR), si_d(NM), si_s(NM)
  int* cnt_base = (int*)alloc(sizeof(int) * CNT_TOTAL);
  int* cnt_sm_d = cnt_base;
  int* cnt_sm_s = cnt_sm_d + NMN;
  int* cnt_rm_d = cnt_sm_s + NSN;
  int* cnt_rm_s = cnt_rm_d + NMN;
  int* cnt_si_d = cnt_rm_s + NRN;
  int* cnt_si_s = cnt_si_d + NMN;

  int* off_base = (int*)alloc(sizeof(int) * (CNT_TOTAL + 1));
  int* off_sm  = off_base;              // NM+1 (end = start of next group)
  int* off_ms  = off_sm + NMN;          // NS+1
  int* off_rm  = off_ms + NSN;          // NM+1
  int* off_mr  = off_rm + NMN;          // NR+1
  int* off_si  = off_mr + NRN;          // NM+1
  int* off_si2 = off_si + NMN;          // NM+1 (last entry = POOL_TOTAL)

  int* bsum = (int*)alloc(sizeof(int) * 512);
  int* pool = (int*)alloc(sizeof(int) * POOL_TOTAL);  // all 6 adjacency lists

  float* dinv1 = (float*)alloc(sizeof(float) * NMN);
  float* dinv2 = (float*)alloc(sizeof(float) * NMN);

  unsigned* xsb = (unsigned*)alloc(sizeof(unsigned) * (size_t)NSN * 64);
  unsigned* xmb = (unsigned*)alloc(sizeof(unsigned) * (size_t)NMN * 64);
  unsigned* xrb = (unsigned*)alloc(sizeof(unsigned) * (size_t)NRN * 64);
  unsigned* xs0 = (unsigned*)alloc(sizeof(unsigned) * (size_t)NSN * 64);
  unsigned* xs1 = (unsigned*)alloc(sizeof(unsigned) * (size_t)NSN * 64);
  unsigned* xm0 = (unsigned*)alloc(sizeof(unsigned) * (size_t)NMN * 64);
  unsigned* xm1 = (unsigned*)alloc(sizeof(unsigned) * (size_t)NMN * 64);
  unsigned* xr0 = (unsigned*)alloc(sizeof(unsigned) * (size_t)NRN * 64);
  unsigned* xr1 = (unsigned*)alloc(sizeof(unsigned) * (size_t)NRN * 64);
  unsigned* aggA = (unsigned*)alloc(sizeof(unsigned) * (size_t)NMN * 64);
  unsigned* aggB = (unsigned*)alloc(sizeof(unsigned) * (size_t)NMN * 64);
  unsigned* aggC = (unsigned*)alloc(sizeof(unsigned) * (size_t)NMN * 64);
  unsigned* aggD = (unsigned*)alloc(sizeof(unsigned) * (size_t)NMN * 64);

  unsigned short* wt = (unsigned short*)alloc(sizeof(unsigned short) * 18 * 16384);
  float* biasM = (float*)alloc(sizeof(float) * 2 * 128);

  auto WT = [&](int l, int slot) -> const unsigned short* {
    return wt + (((size_t)l * 9 + slot) << 14);
  };

  // ---- CSR build ----
  zero_int<<<(CNT_TOTAL + 255) / 256, 256, 0, stream>>>(cnt_base, CNT_TOTAL);
  hist2<<<(ESM + 255) / 256, 256, 0, stream>>>(src_sm, dst_sm, ESM, cnt_sm_d, cnt_sm_s);
  hist2<<<(ERM + 255) / 256, 256, 0, stream>>>(src_rm, dst_rm, ERM, cnt_rm_d, cnt_rm_s);
  hist2<<<(ESIM + 255) / 256, 256, 0, stream>>>(src_sim, dst_sim, ESIM, cnt_si_d, cnt_si_s);

  const int NB = (CNT_TOTAL + 1023) / 1024;  // 398
  scan_partial<<<NB, 256, 0, stream>>>(cnt_base, CNT_TOTAL, bsum);
  scan_bsum<<<1, 512, 0, stream>>>(bsum, NB, off_base + CNT_TOTAL);
  scan_write<<<NB, 256, 0, stream>>>(cnt_base, CNT_TOTAL, bsum, off_base);

  zero_int<<<(CNT_TOTAL + 255) / 256, 256, 0, stream>>>(cnt_base, CNT_TOTAL);  // cursors
  // region divisors: ceil(N/8)
  fillcsr2_rb<12500, 625><<<((ESM + FILL_CH - 1) / FILL_CH) * 8, 256, 0, stream>>>(
      src_sm, dst_sm, ESM, off_sm, cnt_sm_d, off_ms, cnt_sm_s, pool);
  fillcsr2_rb<12500, 250><<<((ERM + FILL_CH - 1) / FILL_CH) * 8, 256, 0, stream>>>(
      src_rm, dst_rm, ERM, off_rm, cnt_rm_d, off_mr, cnt_rm_s, pool);
  fillcsr2_rb<12500, 12500><<<((ESIM + FILL_CH - 1) / FILL_CH) * 8, 256, 0, stream>>>(
      src_sim, dst_sim, ESIM, off_si, cnt_si_d, off_si2, cnt_si_s, pool);

  compute_dinv<<<(NMN + 255) / 256, 256, 0, stream>>>(off_si, off_si2, dinv1, dinv2, NMN);
  trans_weights<<<(18 * 16384 + 255) / 256, 256, 0, stream>>>(sWl, sWr, gW, wt);
  prep_bias<<<1, 256, 0, stream>>>(sbl, gb, biasM);
  cast_all<<<(NMN * 64 + 255) / 256, 256, 0, stream>>>((const float2*)emb_s, (const float2*)emb_m,
                                                       (const float2*)emb_r, xsb, xmb, xrb);

  for (int l = 0; l < 2; ++l) {
    const unsigned* xs_c = l ? xs0 : xsb;
    const unsigned* xm_c = l ? xm0 : xmb;
    const unsigned* xr_c = l ? xr0 : xrb;
    unsigned* xs_n = l ? xs1 : xs0;
    unsigned* xm_n = l ? xm1 : xm0;
    unsigned* xr_n = l ? xr1 : xr0;

    sage_agg<<<(NMN + 3) / 4, 256, 0, stream>>>(xs_c, pool, off_sm, aggA, NMN);
    sage_agg<<<(NMN + 3) / 4, 256, 0, stream>>>(xr_c, pool, off_rm, aggB, NMN);
    gcn_agg<<<(NMN + 3) / 4, 256, 0, stream>>>(xm_c, pool, off_si, dinv1, aggC, NMN);
    gcn_agg<<<(NMN + 3) / 4, 256, 0, stream>>>(xm_c, pool, off_si2, dinv2, aggD, NMN);
    gemm_mfma<<<(NMN + 63) / 64, 256, 0, stream>>>(
        (const unsigned short*)aggA, WT(l, 0), (const unsigned short*)aggB, WT(l, 2),
        (const unsigned short*)aggC, WT(l, 4), (const unsigned short*)aggD, WT(l, 5),
        (const unsigned short*)xm_c, WT(l, 6), biasM + l * 128,
        (unsigned short*)xm_n, NMN);

    sage_agg_mw<<<NSN, 256, 0, stream>>>(xm_c, pool, off_ms, aggA, NSN);
    gemm_mfma<<<(NSN + 63) / 64, 256, 0, stream>>>(
        (const unsigned short*)aggA, WT(l, 1), (const unsigned short*)xs_c, WT(l, 7),
        nullptr, nullptr, nullptr, nullptr, nullptr, nullptr,
        sbl + (l * 4 + 1) * 128, (unsigned short*)xs_n, NSN);

    sage_agg_mw<<<NRN, 256, 0, stream>>>(xm_c, pool, off_mr, aggB, NRN);
    gemm_mfma<<<(NRN + 63) / 64, 256, 0, stream>>>(
        (const unsigned short*)aggB, WT(l, 3), (const unsigned short*)xr_c, WT(l, 8),
        nullptr, nullptr, nullptr, nullptr, nullptr, nullptr,
        sbl + (l * 4 + 3) * 128, (unsigned short*)xr_n, NRN);
  }

  dots_kernel<<<(LBL + 3) / 4, 256, 0, stream>>>(xs1, xm1, xr1, lbl_s, lbl_m, lbl_r, out);
}

// Round 5
// 2093.667 us; speedup vs baseline: 1.1259x; 1.1259x over previous
//
#include <hip/hip_runtime.h>
#include <hip/hip_bf16.h>

#define NSN 5000
#define NMN 100000
#define NRN 2000
#define HDIM 128
#define ESM 2000000
#define ERM 1000000
#define ESIM 2000000
#define LBL 500000

#define CNT_TOTAL (4 * NMN + NSN + NRN)  // 407000
#define POOL_TOTAL (2 * ESM + 2 * ERM + 2 * ESIM)  // 10M

typedef short bf16x8 __attribute__((ext_vector_type(8)));
typedef float f32x4 __attribute__((ext_vector_type(4)));

__device__ __forceinline__ unsigned short f2bf(float f) {
  unsigned u = __float_as_uint(f);
  unsigned r = (u + 0x7fffu + ((u >> 16) & 1u)) >> 16;  // RNE
  return (unsigned short)r;
}
__device__ __forceinline__ float bf_lo(unsigned v) { return __uint_as_float(v << 16); }
__device__ __forceinline__ float bf_hi(unsigned v) { return __uint_as_float(v & 0xffff0000u); }
__device__ __forceinline__ unsigned pack2(float x, float y) {
  return (unsigned)f2bf(x) | ((unsigned)f2bf(y) << 16);
}
// unpack uint4 (8 bf16) -> 8 floats
__device__ __forceinline__ void unpack8(uint4 v, float* f) {
  f[0] = bf_lo(v.x); f[1] = bf_hi(v.x);
  f[2] = bf_lo(v.y); f[3] = bf_hi(v.y);
  f[4] = bf_lo(v.z); f[5] = bf_hi(v.z);
  f[6] = bf_lo(v.w); f[7] = bf_hi(v.w);
}

// ---------------- CSR build ----------------

__global__ void zero_int(int* __restrict__ p, int n) {
  int i = blockIdx.x * blockDim.x + threadIdx.x;
  if (i < n) p[i] = 0;
}

__global__ void hist2(const int* __restrict__ a, const int* __restrict__ b, int n,
                      int* __restrict__ cntA, int* __restrict__ cntB) {
  int i = blockIdx.x * blockDim.x + threadIdx.x;
  if (i < n) {
    atomicAdd(&cntA[b[i]], 1);  // dst-indexed
    atomicAdd(&cntB[a[i]], 1);  // src-indexed
  }
}

__global__ void scan_partial(const int* __restrict__ cnt, int n, int* __restrict__ bsum) {
  __shared__ int sdata[256];
  int b = blockIdx.x, t = threadIdx.x;
  int base = b * 1024;
  int s = 0;
  for (int j = t; j < 1024; j += 256) { int i = base + j; if (i < n) s += cnt[i]; }
  sdata[t] = s; __syncthreads();
  for (int o = 128; o > 0; o >>= 1) { if (t < o) sdata[t] += sdata[t + o]; __syncthreads(); }
  if (t == 0) bsum[b] = sdata[0];
}

__global__ void scan_bsum(int* __restrict__ bsum, int nb, int* __restrict__ off_end) {
  __shared__ int buf[512];
  int t = threadIdx.x;  // 512 threads
  int v = (t < nb) ? bsum[t] : 0;
  buf[t] = v; __syncthreads();
  for (int o = 1; o < 512; o <<= 1) {
    int a = (t >= o) ? buf[t - o] : 0;
    __syncthreads();
    buf[t] += a;
    __syncthreads();
  }
  if (t < nb) bsum[t] = buf[t] - v;     // exclusive
  if (t == 511) *off_end = buf[511];    // grand total
}

__global__ void scan_write(const int* __restrict__ cnt, int n, const int* __restrict__ bsum,
                           int* __restrict__ off) {
  __shared__ int buf[256];
  int b = blockIdx.x, t = threadIdx.x;
  int base = b * 1024 + t * 4;
  int v0 = 0, v1 = 0, v2 = 0, v3 = 0;
  if (base + 0 < n) v0 = cnt[base + 0];
  if (base + 1 < n) v1 = cnt[base + 1];
  if (base + 2 < n) v2 = cnt[base + 2];
  if (base + 3 < n) v3 = cnt[base + 3];
  int s = v0 + v1 + v2 + v3;
  buf[t] = s; __syncthreads();
  for (int o = 1; o < 256; o <<= 1) {
    int a = (t >= o) ? buf[t - o] : 0;
    __syncthreads();
    buf[t] += a;
    __syncthreads();
  }
  int run = buf[t] - s + bsum[b];
  if (base + 0 < n) off[base + 0] = run; run += v0;
  if (base + 1 < n) off[base + 1] = run; run += v1;
  if (base + 2 < n) off[base + 2] = run; run += v2;
  if (base + 3 < n) off[base + 3] = run;
}

// plain combined fwd+rev CSR fill (R3 version — R4's region bucketing regressed)
__global__ void fillcsr2(const int* __restrict__ a, const int* __restrict__ b, int n,
                         const int* __restrict__ offA, int* __restrict__ curA,
                         const int* __restrict__ offB, int* __restrict__ curB,
                         int* __restrict__ pool) {
  int i = blockIdx.x * blockDim.x + threadIdx.x;
  if (i < n) {
    int s_ = a[i], d = b[i];
    int p = atomicAdd(&curA[d], 1);
    pool[offA[d] + p] = s_;
    int q = atomicAdd(&curB[s_], 1);
    pool[offB[s_] + q] = d;
  }
}

__global__ void compute_dinv(const int* __restrict__ off1, const int* __restrict__ off2,
                             float* __restrict__ dinv1, float* __restrict__ dinv2, int n) {
  int v = blockIdx.x * blockDim.x + threadIdx.x;
  if (v < n) {
    dinv1[v] = rsqrtf((float)(off1[v + 1] - off1[v] + 1));
    dinv2[v] = rsqrtf((float)(off2[v + 1] - off2[v] + 1));
  }
}

// bf16 transposed weights wt[(l*9+slot)][n][k], slots:
// 0..3 = sage_Wl rel0..3; 4,5 = gcn_W; 6 = Wr0+Wr2; 7 = Wr1; 8 = Wr3
__global__ void trans_weights(const float* __restrict__ sWl, const float* __restrict__ sWr,
                              const float* __restrict__ gW, unsigned short* __restrict__ wt) {
  int i = blockIdx.x * blockDim.x + threadIdx.x;
  if (i >= 18 * 16384) return;
  int mat = i >> 14, l = mat / 9, slot = mat % 9;
  int idx = i & 16383, nn = idx >> 7, kk = idx & 127;
  int s_ = kk * 128 + nn;  // source [k][n] row-major
  float v;
  if (slot < 4)      v = sWl[((l * 4 + slot) << 14) + s_];
  else if (slot < 6) v = gW[((l * 2 + (slot - 4)) << 14) + s_];
  else if (slot == 6) v = sWr[((l * 4 + 0) << 14) + s_] + sWr[((l * 4 + 2) << 14) + s_];
  else if (slot == 7) v = sWr[((l * 4 + 1) << 14) + s_];
  else                v = sWr[((l * 4 + 3) << 14) + s_];
  wt[i] = f2bf(v);
}

__global__ void prep_bias(const float* __restrict__ sbl, const float* __restrict__ gb,
                          float* __restrict__ biasM) {
  int i = threadIdx.x;  // 256 threads
  int l = i >> 7, j = i & 127;
  biasM[i] = sbl[(l * 4 + 0) * 128 + j] + sbl[(l * 4 + 2) * 128 + j] +
             gb[(l * 2 + 0) * 128 + j] + gb[(l * 2 + 1) * 128 + j];
}

__global__ void cast_all(const float2* __restrict__ es, const float2* __restrict__ em,
                         const float2* __restrict__ er, unsigned* __restrict__ os,
                         unsigned* __restrict__ om, unsigned* __restrict__ orr) {
  int i = blockIdx.x * blockDim.x + threadIdx.x;
  if (i < NSN * 64) { float2 v = es[i]; os[i] = pack2(v.x, v.y); }
  if (i < NMN * 64) { float2 v = em[i]; om[i] = pack2(v.x, v.y); }
  if (i < NRN * 64) { float2 v = er[i]; orr[i] = pack2(v.x, v.y); }
}

// ---------------- aggregation (quarter-wave uint4 gathers) ----------------
// Wave = 4 groups x 16 lanes. Group q handles edge i+q; lane h (=lane&15)
// covers dims 8h..8h+7 via one uint4 (16B) load -> 4 rows (1KB) per wave-instr.
// End: butterfly shfl_xor(16,32) combines groups; q==0 lanes write the row.

__global__ void sage_agg(const unsigned* __restrict__ x, const int* __restrict__ pool,
                         const int* __restrict__ off, unsigned* __restrict__ outb, int n) {
  int w = (blockIdx.x * blockDim.x + threadIdx.x) >> 6;
  if (w >= n) return;
  int lane = threadIdx.x & 63;
  int q = lane >> 4, h = lane & 15;
  int s = off[w], e = off[w + 1];
  float acc[8];
#pragma unroll
  for (int j = 0; j < 8; j++) acc[j] = 0.f;
  for (int i0 = s; i0 < e; i0 += 8) {
    int iA = i0 + q, iB = i0 + 4 + q;
    int uA = pool[min(iA, e - 1)], uB = pool[min(iB, e - 1)];
    uint4 a = *(const uint4*)(x + (size_t)uA * 64 + h * 4);
    uint4 b = *(const uint4*)(x + (size_t)uB * 64 + h * 4);
    float sA = (iA < e) ? 1.f : 0.f, sB = (iB < e) ? 1.f : 0.f;
    float fa[8], fb[8];
    unpack8(a, fa); unpack8(b, fb);
#pragma unroll
    for (int j = 0; j < 8; j++) acc[j] = fmaf(fa[j], sA, fmaf(fb[j], sB, acc[j]));
  }
#pragma unroll
  for (int j = 0; j < 8; j++) {
    acc[j] += __shfl_xor(acc[j], 16, 64);
    acc[j] += __shfl_xor(acc[j], 32, 64);
  }
  if (q == 0) {
    float inv = (e > s) ? 1.0f / (float)(e - s) : 0.0f;
    uint4 o;
    o.x = pack2(acc[0] * inv, acc[1] * inv);
    o.y = pack2(acc[2] * inv, acc[3] * inv);
    o.z = pack2(acc[4] * inv, acc[5] * inv);
    o.w = pack2(acc[6] * inv, acc[7] * inv);
    *(uint4*)(outb + (size_t)w * 64 + h * 4) = o;
  }
}

__global__ void gcn_agg(const unsigned* __restrict__ x, const int* __restrict__ pool,
                        const int* __restrict__ off, const float* __restrict__ dinv,
                        unsigned* __restrict__ outb, int n) {
  int w = (blockIdx.x * blockDim.x + threadIdx.x) >> 6;
  if (w >= n) return;
  int lane = threadIdx.x & 63;
  int q = lane >> 4, h = lane & 15;
  int s = off[w], e = off[w + 1];
  float acc[8];
#pragma unroll
  for (int j = 0; j < 8; j++) acc[j] = 0.f;
  for (int i0 = s; i0 < e; i0 += 8) {
    int iA = i0 + q, iB = i0 + 4 + q;
    int uA = pool[min(iA, e - 1)], uB = pool[min(iB, e - 1)];
    uint4 a = *(const uint4*)(x + (size_t)uA * 64 + h * 4);
    uint4 b = *(const uint4*)(x + (size_t)uB * 64 + h * 4);
    float sA = (iA < e) ? dinv[uA] : 0.f, sB = (iB < e) ? dinv[uB] : 0.f;
    float fa[8], fb[8];
    unpack8(a, fa); unpack8(b, fb);
#pragma unroll
    for (int j = 0; j < 8; j++) acc[j] = fmaf(fa[j], sA, fmaf(fb[j], sB, acc[j]));
  }
#pragma unroll
  for (int j = 0; j < 8; j++) {
    acc[j] += __shfl_xor(acc[j], 16, 64);
    acc[j] += __shfl_xor(acc[j], 32, 64);
  }
  if (q == 0) {
    float dw = dinv[w];
    uint4 xv = *(const uint4*)(x + (size_t)w * 64 + h * 4);
    float fx[8];
    unpack8(xv, fx);
    uint4 o;
    float r0 = acc[0] * dw + fx[0] * dw * dw, r1 = acc[1] * dw + fx[1] * dw * dw;
    float r2 = acc[2] * dw + fx[2] * dw * dw, r3 = acc[3] * dw + fx[3] * dw * dw;
    float r4 = acc[4] * dw + fx[4] * dw * dw, r5 = acc[5] * dw + fx[5] * dw * dw;
    float r6 = acc[6] * dw + fx[6] * dw * dw, r7 = acc[7] * dw + fx[7] * dw * dw;
    o.x = pack2(r0, r1); o.y = pack2(r2, r3); o.z = pack2(r4, r5); o.w = pack2(r6, r7);
    *(uint4*)(outb + (size_t)w * 64 + h * 4) = o;
  }
}

// 4 waves per dst node (NS/NR targets, deg ~400-500); each wave 4 edges/iter.
__global__ __launch_bounds__(256) void sage_agg_mw(const unsigned* __restrict__ x,
                                                   const int* __restrict__ pool,
                                                   const int* __restrict__ off,
                                                   unsigned* __restrict__ outb, int n) {
  __shared__ float psum[3][128];
  int node = blockIdx.x;
  if (node >= n) return;
  int sub = threadIdx.x >> 6, lane = threadIdx.x & 63;
  int q = lane >> 4, h = lane & 15;
  int s = off[node], e = off[node + 1];
  float acc[8];
#pragma unroll
  for (int j = 0; j < 8; j++) acc[j] = 0.f;
  for (int i0 = s + sub * 4; i0 < e; i0 += 16) {
    int idx = i0 + q;
    int u = pool[min(idx, e - 1)];
    uint4 a = *(const uint4*)(x + (size_t)u * 64 + h * 4);
    float sc = (idx < e) ? 1.f : 0.f;
    float fa[8];
    unpack8(a, fa);
#pragma unroll
    for (int j = 0; j < 8; j++) acc[j] = fmaf(fa[j], sc, acc[j]);
  }
#pragma unroll
  for (int j = 0; j < 8; j++) {
    acc[j] += __shfl_xor(acc[j], 16, 64);
    acc[j] += __shfl_xor(acc[j], 32, 64);
  }
  if (sub && q == 0) {
#pragma unroll
    for (int j = 0; j < 8; j++) psum[sub - 1][h * 8 + j] = acc[j];
  }
  __syncthreads();
  if (sub == 0 && q == 0) {
#pragma unroll
    for (int j = 0; j < 8; j++)
      acc[j] += psum[0][h * 8 + j] + psum[1][h * 8 + j] + psum[2][h * 8 + j];
    float inv = (e > s) ? 1.0f / (float)(e - s) : 0.0f;
    uint4 o;
    o.x = pack2(acc[0] * inv, acc[1] * inv);
    o.y = pack2(acc[2] * inv, acc[3] * inv);
    o.z = pack2(acc[4] * inv, acc[5] * inv);
    o.w = pack2(acc[6] * inv, acc[7] * inv);
    *(uint4*)(outb + (size_t)node * 64 + h * 4) = o;
  }
}

// ---------------- MFMA GEMM: out = relu(bias + sum_p A_p @ W_p) ----------------

#define LDA 136

__global__ __launch_bounds__(256) void gemm_mfma(
    const unsigned short* __restrict__ a0, const unsigned short* __restrict__ w0,
    const unsigned short* __restrict__ a1, const unsigned short* __restrict__ w1,
    const unsigned short* __restrict__ a2, const unsigned short* __restrict__ w2,
    const unsigned short* __restrict__ a3, const unsigned short* __restrict__ w3,
    const unsigned short* __restrict__ a4, const unsigned short* __restrict__ w4,
    const float* __restrict__ bias, unsigned short* __restrict__ out, int n) {
  __shared__ __align__(16) unsigned short As[64 * LDA];
  __shared__ __align__(16) unsigned short Ws[128 * LDA];

  int tid = threadIdx.x;
  int w = tid >> 6, lane = tid & 63;
  int q = lane >> 4, c = lane & 15;
  int r0 = blockIdx.x * 64;

  const unsigned short* Ap[5] = {a0, a1, a2, a3, a4};
  const unsigned short* Wp[5] = {w0, w1, w2, w3, w4};

  float bias_v[8];
#pragma unroll
  for (int n0 = 0; n0 < 8; n0++) bias_v[n0] = bias[n0 * 16 + c];

  f32x4 acc[8];
#pragma unroll
  for (int n0 = 0; n0 < 8; n0++) acc[n0] = (f32x4){0.f, 0.f, 0.f, 0.f};

  for (int p = 0; p < 5; p++) {
    if (!Ap[p]) continue;
    __syncthreads();
    for (int j = tid; j < 2048; j += 256) {
      int row = j >> 4, colc = (j & 15) * 8;
      *(uint4*)&Ws[row * LDA + colc] = *(const uint4*)(Wp[p] + row * 128 + colc);
    }
    for (int j = tid; j < 1024; j += 256) {
      int row = j >> 4, colc = (j & 15) * 8;
      uint4 v = make_uint4(0u, 0u, 0u, 0u);
      if (r0 + row < n) v = *(const uint4*)(Ap[p] + (size_t)(r0 + row) * 128 + colc);
      *(uint4*)&As[row * LDA + colc] = v;
    }
    __syncthreads();

    int arow = (w * 16 + c) * LDA;
#pragma unroll
    for (int k0 = 0; k0 < 128; k0 += 32) {
      bf16x8 af = *(const bf16x8*)&As[arow + k0 + q * 8];
#pragma unroll
      for (int n0 = 0; n0 < 8; n0++) {
        bf16x8 bfv = *(const bf16x8*)&Ws[(n0 * 16 + c) * LDA + k0 + q * 8];
        acc[n0] = __builtin_amdgcn_mfma_f32_16x16x32_bf16(af, bfv, acc[n0], 0, 0, 0);
      }
    }
  }

  __syncthreads();
#pragma unroll
  for (int n0 = 0; n0 < 8; n0++) {
#pragma unroll
    for (int reg = 0; reg < 4; reg++) {
      float v = acc[n0][reg] + bias_v[n0];
      v = fmaxf(v, 0.f);
      As[(w * 16 + q * 4 + reg) * LDA + n0 * 16 + c] = f2bf(v);
    }
  }
  __syncthreads();
  for (int j = tid; j < 1024; j += 256) {
    int row = j >> 4, colc = (j & 15) * 8;
    if (r0 + row < n)
      *(uint4*)(out + (size_t)(r0 + row) * 128 + colc) = *(const uint4*)&As[row * LDA + colc];
  }
}

// ---------------- final dot products (4 pairs per wave, quarter-wave each) ----

__global__ void dots_kernel(const unsigned* __restrict__ xs, const unsigned* __restrict__ xm,
                            const unsigned* __restrict__ xr, const int* __restrict__ ls,
                            const int* __restrict__ lm, const int* __restrict__ lr,
                            float* __restrict__ out) {
  int wv = (blockIdx.x * blockDim.x + threadIdx.x) >> 6;
  int lane = threadIdx.x & 63;
  int q = lane >> 4, h = lane & 15;
  int i = wv * 4 + q;
  if (i >= LBL) return;
  int im = lm[i], is = ls[i], ir = lr[i];
  uint4 mv = *(const uint4*)(xm + (size_t)im * 64 + h * 4);
  uint4 sv = *(const uint4*)(xs + (size_t)is * 64 + h * 4);
  uint4 rv = *(const uint4*)(xr + (size_t)ir * 64 + h * 4);
  float fm[8], fs[8], fr[8];
  unpack8(mv, fm); unpack8(sv, fs); unpack8(rv, fr);
  float p1 = 0.f, p2 = 0.f;
#pragma unroll
  for (int j = 0; j < 8; j++) { p1 = fmaf(fs[j], fm[j], p1); p2 = fmaf(fr[j], fm[j], p2); }
#pragma unroll
  for (int m = 1; m < 16; m <<= 1) {
    p1 += __shfl_xor(p1, m, 64);
    p2 += __shfl_xor(p2, m, 64);
  }
  if (h == 0) { out[i] = p1; out[LBL + i] = p2; }
}

// ---------------- host launcher ----------------

extern "C" void kernel_launch(void* const* d_in, const int* in_sizes, int n_in,
                              void* d_out, int out_size, void* d_ws, size_t ws_size,
                              hipStream_t stream) {
  const float* emb_s = (const float*)d_in[0];
  const float* emb_m = (const float*)d_in[1];
  const float* emb_r = (const float*)d_in[2];
  const float* sWl = (const float*)d_in[3];
  const float* sbl = (const float*)d_in[4];
  const float* sWr = (const float*)d_in[5];
  const float* gW  = (const float*)d_in[6];
  const float* gb  = (const float*)d_in[7];
  const int* src_sm  = (const int*)d_in[8];
  const int* dst_sm  = (const int*)d_in[9];
  const int* src_rm  = (const int*)d_in[10];
  const int* dst_rm  = (const int*)d_in[11];
  const int* src_sim = (const int*)d_in[12];
  const int* dst_sim = (const int*)d_in[13];
  const int* lbl_s = (const int*)d_in[14];
  const int* lbl_m = (const int*)d_in[15];
  const int* lbl_r = (const int*)d_in[16];
  float* out = (float*)d_out;

  char* p = (char*)d_ws;
  auto alloc = [&](size_t bytes) -> char* {
    char* r = p;
    p += (bytes + 255) & ~(size_t)255;
    return r;
  };

  int* cnt_base = (int*)alloc(sizeof(int) * CNT_TOTAL);
  int* cnt_sm_d = cnt_base;
  int* cnt_sm_s = cnt_sm_d + NMN;
  int* cnt_rm_d = cnt_sm_s + NSN;
  int* cnt_rm_s = cnt_rm_d + NMN;
  int* cnt_si_d = cnt_rm_s + NRN;
  int* cnt_si_s = cnt_si_d + NMN;

  int* off_base = (int*)alloc(sizeof(int) * (CNT_TOTAL + 1));
  int* off_sm  = off_base;
  int* off_ms  = off_sm + NMN;
  int* off_rm  = off_ms + NSN;
  int* off_mr  = off_rm + NMN;
  int* off_si  = off_mr + NRN;
  int* off_si2 = off_si + NMN;

  int* bsum = (int*)alloc(sizeof(int) * 512);
  int* pool = (int*)alloc(sizeof(int) * POOL_TOTAL);

  float* dinv1 = (float*)alloc(sizeof(float) * NMN);
  float* dinv2 = (float*)alloc(sizeof(float) * NMN);

  unsigned* xsb = (unsigned*)alloc(sizeof(unsigned) * (size_t)NSN * 64);
  unsigned* xmb = (unsigned*)alloc(sizeof(unsigned) * (size_t)NMN * 64);
  unsigned* xrb = (unsigned*)alloc(sizeof(unsigned) * (size_t)NRN * 64);
  unsigned* xs0 = (unsigned*)alloc(sizeof(unsigned) * (size_t)NSN * 64);
  unsigned* xs1 = (unsigned*)alloc(sizeof(unsigned) * (size_t)NSN * 64);
  unsigned* xm0 = (unsigned*)alloc(sizeof(unsigned) * (size_t)NMN * 64);
  unsigned* xm1 = (unsigned*)alloc(sizeof(unsigned) * (size_t)NMN * 64);
  unsigned* xr0 = (unsigned*)alloc(sizeof(unsigned) * (size_t)NRN * 64);
  unsigned* xr1 = (unsigned*)alloc(sizeof(unsigned) * (size_t)NRN * 64);
  unsigned* aggA = (unsigned*)alloc(sizeof(unsigned) * (size_t)NMN * 64);
  unsigned* aggB = (unsigned*)alloc(sizeof(unsigned) * (size_t)NMN * 64);
  unsigned* aggC = (unsigned*)alloc(sizeof(unsigned) * (size_t)NMN * 64);
  unsigned* aggD = (unsigned*)alloc(sizeof(unsigned) * (size_t)NMN * 64);

  unsigned short* wt = (unsigned short*)alloc(sizeof(unsigned short) * 18 * 16384);
  float* biasM = (float*)alloc(sizeof(float) * 2 * 128);

  auto WT = [&](int l, int slot) -> const unsigned short* {
    return wt + (((size_t)l * 9 + slot) << 14);
  };

  // ---- CSR build ----
  zero_int<<<(CNT_TOTAL + 255) / 256, 256, 0, stream>>>(cnt_base, CNT_TOTAL);
  hist2<<<(ESM + 255) / 256, 256, 0, stream>>>(src_sm, dst_sm, ESM, cnt_sm_d, cnt_sm_s);
  hist2<<<(ERM + 255) / 256, 256, 0, stream>>>(src_rm, dst_rm, ERM, cnt_rm_d, cnt_rm_s);
  hist2<<<(ESIM + 255) / 256, 256, 0, stream>>>(src_sim, dst_sim, ESIM, cnt_si_d, cnt_si_s);

  const int NB = (CNT_TOTAL + 1023) / 1024;  // 398
  scan_partial<<<NB, 256, 0, stream>>>(cnt_base, CNT_TOTAL, bsum);
  scan_bsum<<<1, 512, 0, stream>>>(bsum, NB, off_base + CNT_TOTAL);
  scan_write<<<NB, 256, 0, stream>>>(cnt_base, CNT_TOTAL, bsum, off_base);

  zero_int<<<(CNT_TOTAL + 255) / 256, 256, 0, stream>>>(cnt_base, CNT_TOTAL);
  fillcsr2<<<(ESM + 255) / 256, 256, 0, stream>>>(src_sm, dst_sm, ESM,
                                                  off_sm, cnt_sm_d, off_ms, cnt_sm_s, pool);
  fillcsr2<<<(ERM + 255) / 256, 256, 0, stream>>>(src_rm, dst_rm, ERM,
                                                  off_rm, cnt_rm_d, off_mr, cnt_rm_s, pool);
  fillcsr2<<<(ESIM + 255) / 256, 256, 0, stream>>>(src_sim, dst_sim, ESIM,
                                                   off_si, cnt_si_d, off_si2, cnt_si_s, pool);

  compute_dinv<<<(NMN + 255) / 256, 256, 0, stream>>>(off_si, off_si2, dinv1, dinv2, NMN);
  trans_weights<<<(18 * 16384 + 255) / 256, 256, 0, stream>>>(sWl, sWr, gW, wt);
  prep_bias<<<1, 256, 0, stream>>>(sbl, gb, biasM);
  cast_all<<<(NMN * 64 + 255) / 256, 256, 0, stream>>>((const float2*)emb_s, (const float2*)emb_m,
                                                       (const float2*)emb_r, xsb, xmb, xrb);

  for (int l = 0; l < 2; ++l) {
    const unsigned* xs_c = l ? xs0 : xsb;
    const unsigned* xm_c = l ? xm0 : xmb;
    const unsigned* xr_c = l ? xr0 : xrb;
    unsigned* xs_n = l ? xs1 : xs0;
    unsigned* xm_n = l ? xm1 : xm0;
    unsigned* xr_n = l ? xr1 : xr0;

    sage_agg<<<(NMN + 3) / 4, 256, 0, stream>>>(xs_c, pool, off_sm, aggA, NMN);
    sage_agg<<<(NMN + 3) / 4, 256, 0, stream>>>(xr_c, pool, off_rm, aggB, NMN);
    gcn_agg<<<(NMN + 3) / 4, 256, 0, stream>>>(xm_c, pool, off_si, dinv1, aggC, NMN);
    gcn_agg<<<(NMN + 3) / 4, 256, 0, stream>>>(xm_c, pool, off_si2, dinv2, aggD, NMN);
    gemm_mfma<<<(NMN + 63) / 64, 256, 0, stream>>>(
        (const unsigned short*)aggA, WT(l, 0), (const unsigned short*)aggB, WT(l, 2),
        (const unsigned short*)aggC, WT(l, 4), (const unsigned short*)aggD, WT(l, 5),
        (const unsigned short*)xm_c, WT(l, 6), biasM + l * 128,
        (unsigned short*)xm_n, NMN);

    sage_agg_mw<<<NSN, 256, 0, stream>>>(xm_c, pool, off_ms, aggA, NSN);
    gemm_mfma<<<(NSN + 63) / 64, 256, 0, stream>>>(
        (const unsigned short*)aggA, WT(l, 1), (const unsigned short*)xs_c, WT(l, 7),
        nullptr, nullptr, nullptr, nullptr, nullptr, nullptr,
        sbl + (l * 4 + 1) * 128, (unsigned short*)xs_n, NSN);

    sage_agg_mw<<<NRN, 256, 0, stream>>>(xm_c, pool, off_mr, aggB, NRN);
    gemm_mfma<<<(NRN + 63) / 64, 256, 0, stream>>>(
        (const unsigned short*)aggB, WT(l, 3), (const unsigned short*)xr_c, WT(l, 8),
        nullptr, nullptr, nullptr, nullptr, nullptr, nullptr,
        sbl + (l * 4 + 3) * 128, (unsigned short*)xr_n, NRN);
  }

  dots_kernel<<<(LBL * 16 + 255) / 256, 256, 0, stream>>>(xs1, xm1, xr1, lbl_s, lbl_m, lbl_r, out);
}

// Round 6
// 1987.098 us; speedup vs baseline: 1.1862x; 1.0536x over previous
//
#include <hip/hip_runtime.h>
#include <hip/hip_bf16.h>

#define NSN 5000
#define NMN 100000
#define NRN 2000
#define HDIM 128
#define ESM 2000000
#define ERM 1000000
#define ESIM 2000000
#define LBL 500000

#define CNT_TOTAL (4 * NMN + NSN + NRN)  // 407000
#define POOL_TOTAL (2 * ESM + 2 * ERM + 2 * ESIM)  // 10M
#define NBTOT 485

typedef short bf16x8 __attribute__((ext_vector_type(8)));
typedef float f32x4 __attribute__((ext_vector_type(4)));

__device__ __forceinline__ unsigned short f2bf(float f) {
  unsigned u = __float_as_uint(f);
  unsigned r = (u + 0x7fffu + ((u >> 16) & 1u)) >> 16;  // RNE
  return (unsigned short)r;
}
__device__ __forceinline__ float bf_lo(unsigned v) { return __uint_as_float(v << 16); }
__device__ __forceinline__ float bf_hi(unsigned v) { return __uint_as_float(v & 0xffff0000u); }
__device__ __forceinline__ unsigned pack2(float x, float y) {
  return (unsigned)f2bf(x) | ((unsigned)f2bf(y) << 16);
}
__device__ __forceinline__ void unpack8(uint4 v, float* f) {
  f[0] = bf_lo(v.x); f[1] = bf_hi(v.x);
  f[2] = bf_lo(v.y); f[3] = bf_hi(v.y);
  f[4] = bf_lo(v.z); f[5] = bf_hi(v.z);
  f[6] = bf_lo(v.w); f[7] = bf_hi(v.w);
}

// ---------------- CSR build ----------------

__global__ void zero_int(int* __restrict__ p, int n) {
  int i = blockIdx.x * blockDim.x + threadIdx.x;
  if (i < n) p[i] = 0;
}

__global__ void hist2(const int* __restrict__ a, const int* __restrict__ b, int n,
                      int* __restrict__ cntA, int* __restrict__ cntB) {
  int i = blockIdx.x * blockDim.x + threadIdx.x;
  if (i < n) {
    atomicAdd(&cntA[b[i]], 1);  // dst-indexed
    atomicAdd(&cntB[a[i]], 1);  // src-indexed
  }
}

__global__ void scan_partial(const int* __restrict__ cnt, int n, int* __restrict__ bsum) {
  __shared__ int sdata[256];
  int b = blockIdx.x, t = threadIdx.x;
  int base = b * 1024;
  int s = 0;
  for (int j = t; j < 1024; j += 256) { int i = base + j; if (i < n) s += cnt[i]; }
  sdata[t] = s; __syncthreads();
  for (int o = 128; o > 0; o >>= 1) { if (t < o) sdata[t] += sdata[t + o]; __syncthreads(); }
  if (t == 0) bsum[b] = sdata[0];
}

__global__ void scan_bsum(int* __restrict__ bsum, int nb, int* __restrict__ off_end) {
  __shared__ int buf[512];
  int t = threadIdx.x;  // 512 threads
  int v = (t < nb) ? bsum[t] : 0;
  buf[t] = v; __syncthreads();
  for (int o = 1; o < 512; o <<= 1) {
    int a = (t >= o) ? buf[t - o] : 0;
    __syncthreads();
    buf[t] += a;
    __syncthreads();
  }
  if (t < nb) bsum[t] = buf[t] - v;     // exclusive
  if (t == 511) *off_end = buf[511];    // grand total
}

__global__ void scan_write(const int* __restrict__ cnt, int n, const int* __restrict__ bsum,
                           int* __restrict__ off) {
  __shared__ int buf[256];
  int b = blockIdx.x, t = threadIdx.x;
  int base = b * 1024 + t * 4;
  int v0 = 0, v1 = 0, v2 = 0, v3 = 0;
  if (base + 0 < n) v0 = cnt[base + 0];
  if (base + 1 < n) v1 = cnt[base + 1];
  if (base + 2 < n) v2 = cnt[base + 2];
  if (base + 3 < n) v3 = cnt[base + 3];
  int s = v0 + v1 + v2 + v3;
  buf[t] = s; __syncthreads();
  for (int o = 1; o < 256; o <<= 1) {
    int a = (t >= o) ? buf[t - o] : 0;
    __syncthreads();
    buf[t] += a;
    __syncthreads();
  }
  int run = buf[t] - s + bsum[b];
  if (base + 0 < n) off[base + 0] = run; run += v0;
  if (base + 1 < n) off[base + 1] = run; run += v1;
  if (base + 2 < n) off[base + 2] = run; run += v2;
  if (base + 3 < n) off[base + 3] = run;
}

// Global bucket table: id -> (node-slot group base g, node range [ns,ne)).
// sm fwd: 0..97 (NM,>>10)   sm rev: 98..176 (NS,>>6)
// rm fwd: 177..225 (NM,>>11) rm rev: 226..288 (NR,>>5)
// si fwd: 289..386 (NM,>>10) si rev: 387..484 (NM,>>10)
struct BInfo { int g; int ns; int ne; };
__device__ __forceinline__ BInfo binfo(int id) {
  BInfo bi;
  if (id < 98)       { int k = id;       bi.g = 0;                       bi.ns = k << 10; bi.ne = min((k + 1) << 10, NMN); }
  else if (id < 177) { int k = id - 98;  bi.g = NMN;                     bi.ns = k << 6;  bi.ne = min((k + 1) << 6,  NSN); }
  else if (id < 226) { int k = id - 177; bi.g = NMN + NSN;               bi.ns = k << 11; bi.ne = min((k + 1) << 11, NMN); }
  else if (id < 289) { int k = id - 226; bi.g = 2 * NMN + NSN;           bi.ns = k << 5;  bi.ne = min((k + 1) << 5,  NRN); }
  else if (id < 387) { int k = id - 289; bi.g = 2 * NMN + NSN + NRN;     bi.ns = k << 10; bi.ne = min((k + 1) << 10, NMN); }
  else               { int k = id - 387; bi.g = 3 * NMN + NSN + NRN;     bi.ns = k << 10; bi.ne = min((k + 1) << 10, NMN); }
  return bi;
}

__global__ void init_bcur(const int* __restrict__ offG, int* __restrict__ bcur) {
  int id = blockIdx.x * blockDim.x + threadIdx.x;
  if (id < NBTOT) { BInfo bi = binfo(id); bcur[id] = offG[bi.g + bi.ns]; }
}

// Phase A: multisplit edges into bucket-partitioned (target,payload) staging.
// One 2048-edge tile per block; LDS hist -> one global atomic per (tile,bucket)
// -> pair writes land in per-tile contiguous runs (single-XCD lines, amp ~1x).
template <int SHF, int NBF, int SHR, int NBR>
__global__ __launch_bounds__(256) void multisplit(
    const int* __restrict__ a, const int* __restrict__ b, int n,
    int* __restrict__ bcur, int bb, int* __restrict__ stage) {
  __shared__ int hist[NBF + NBR];
  __shared__ int gpos[NBF + NBR];
  int tid = threadIdx.x;
  int base = blockIdx.x * 2048;
  for (int k = tid; k < NBF + NBR; k += 256) hist[k] = 0;
  __syncthreads();
  int dv[8], sv[8];
#pragma unroll
  for (int j = 0; j < 8; j++) {
    int idx = base + j * 256 + tid;
    if (idx < n) {
      sv[j] = a[idx]; dv[j] = b[idx];
      atomicAdd(&hist[dv[j] >> SHF], 1);
      atomicAdd(&hist[NBF + (sv[j] >> SHR)], 1);
    } else {
      dv[j] = -1;
    }
  }
  __syncthreads();
  for (int k = tid; k < NBF + NBR; k += 256) {
    int c = hist[k];
    gpos[k] = c ? atomicAdd(&bcur[bb + k], c) : 0;
  }
  __syncthreads();
#pragma unroll
  for (int j = 0; j < 8; j++) {
    if (dv[j] >= 0) {
      int s1 = atomicAdd(&gpos[dv[j] >> SHF], 1);
      stage[2 * s1] = dv[j]; stage[2 * s1 + 1] = sv[j];
      int s2 = atomicAdd(&gpos[NBF + (sv[j] >> SHR)], 1);
      stage[2 * s2] = sv[j]; stage[2 * s2 + 1] = dv[j];
    }
  }
}

// Phase B: one block per bucket; sequential read of staged pairs, scatter into
// the bucket's ~64-100KB pool window (L2-resident on one XCD -> amp ~1x).
__global__ __launch_bounds__(256) void scatter_bucket(
    const int* __restrict__ stage, const int* __restrict__ offG,
    int* __restrict__ cur, int* __restrict__ pool) {
  BInfo bi = binfo(blockIdx.x);
  int s0 = offG[bi.g + bi.ns], s1 = offG[bi.g + bi.ne];
  for (int k = s0 + (int)threadIdx.x; k < s1; k += 256) {
    int d = stage[2 * k], s_ = stage[2 * k + 1];
    int slot = atomicAdd(&cur[bi.g + d], 1);
    pool[offG[bi.g + d] + slot] = s_;
  }
}

__global__ void compute_dinv(const int* __restrict__ off1, const int* __restrict__ off2,
                             float* __restrict__ dinv1, float* __restrict__ dinv2, int n) {
  int v = blockIdx.x * blockDim.x + threadIdx.x;
  if (v < n) {
    dinv1[v] = rsqrtf((float)(off1[v + 1] - off1[v] + 1));
    dinv2[v] = rsqrtf((float)(off2[v + 1] - off2[v] + 1));
  }
}

// bf16 transposed weights wt[(l*9+slot)][n][k], slots:
// 0..3 = sage_Wl rel0..3; 4,5 = gcn_W; 6 = Wr0+Wr2; 7 = Wr1; 8 = Wr3
__global__ void trans_weights(const float* __restrict__ sWl, const float* __restrict__ sWr,
                              const float* __restrict__ gW, unsigned short* __restrict__ wt) {
  int i = blockIdx.x * blockDim.x + threadIdx.x;
  if (i >= 18 * 16384) return;
  int mat = i >> 14, l = mat / 9, slot = mat % 9;
  int idx = i & 16383, nn = idx >> 7, kk = idx & 127;
  int s_ = kk * 128 + nn;  // source [k][n] row-major
  float v;
  if (slot < 4)      v = sWl[((l * 4 + slot) << 14) + s_];
  else if (slot < 6) v = gW[((l * 2 + (slot - 4)) << 14) + s_];
  else if (slot == 6) v = sWr[((l * 4 + 0) << 14) + s_] + sWr[((l * 4 + 2) << 14) + s_];
  else if (slot == 7) v = sWr[((l * 4 + 1) << 14) + s_];
  else                v = sWr[((l * 4 + 3) << 14) + s_];
  wt[i] = f2bf(v);
}

__global__ void prep_bias(const float* __restrict__ sbl, const float* __restrict__ gb,
                          float* __restrict__ biasM) {
  int i = threadIdx.x;  // 256 threads
  int l = i >> 7, j = i & 127;
  biasM[i] = sbl[(l * 4 + 0) * 128 + j] + sbl[(l * 4 + 2) * 128 + j] +
             gb[(l * 2 + 0) * 128 + j] + gb[(l * 2 + 1) * 128 + j];
}

__global__ void cast_all(const float2* __restrict__ es, const float2* __restrict__ em,
                         const float2* __restrict__ er, unsigned* __restrict__ os,
                         unsigned* __restrict__ om, unsigned* __restrict__ orr) {
  int i = blockIdx.x * blockDim.x + threadIdx.x;
  if (i < NSN * 64) { float2 v = es[i]; os[i] = pack2(v.x, v.y); }
  if (i < NMN * 64) { float2 v = em[i]; om[i] = pack2(v.x, v.y); }
  if (i < NRN * 64) { float2 v = er[i]; orr[i] = pack2(v.x, v.y); }
}

// ---------------- aggregation (quarter-wave uint4 gathers) ----------------

__global__ void sage_agg(const unsigned* __restrict__ x, const int* __restrict__ pool,
                         const int* __restrict__ off, unsigned* __restrict__ outb, int n) {
  int w = (blockIdx.x * blockDim.x + threadIdx.x) >> 6;
  if (w >= n) return;
  int lane = threadIdx.x & 63;
  int q = lane >> 4, h = lane & 15;
  int s = off[w], e = off[w + 1];
  float acc[8];
#pragma unroll
  for (int j = 0; j < 8; j++) acc[j] = 0.f;
  for (int i0 = s; i0 < e; i0 += 8) {
    int iA = i0 + q, iB = i0 + 4 + q;
    int uA = pool[min(iA, e - 1)], uB = pool[min(iB, e - 1)];
    uint4 a = *(const uint4*)(x + (size_t)uA * 64 + h * 4);
    uint4 b = *(const uint4*)(x + (size_t)uB * 64 + h * 4);
    float sA = (iA < e) ? 1.f : 0.f, sB = (iB < e) ? 1.f : 0.f;
    float fa[8], fb[8];
    unpack8(a, fa); unpack8(b, fb);
#pragma unroll
    for (int j = 0; j < 8; j++) acc[j] = fmaf(fa[j], sA, fmaf(fb[j], sB, acc[j]));
  }
#pragma unroll
  for (int j = 0; j < 8; j++) {
    acc[j] += __shfl_xor(acc[j], 16, 64);
    acc[j] += __shfl_xor(acc[j], 32, 64);
  }
  if (q == 0) {
    float inv = (e > s) ? 1.0f / (float)(e - s) : 0.0f;
    uint4 o;
    o.x = pack2(acc[0] * inv, acc[1] * inv);
    o.y = pack2(acc[2] * inv, acc[3] * inv);
    o.z = pack2(acc[4] * inv, acc[5] * inv);
    o.w = pack2(acc[6] * inv, acc[7] * inv);
    *(uint4*)(outb + (size_t)w * 64 + h * 4) = o;
  }
}

__global__ void gcn_agg(const unsigned* __restrict__ x, const int* __restrict__ pool,
                        const int* __restrict__ off, const float* __restrict__ dinv,
                        unsigned* __restrict__ outb, int n) {
  int w = (blockIdx.x * blockDim.x + threadIdx.x) >> 6;
  if (w >= n) return;
  int lane = threadIdx.x & 63;
  int q = lane >> 4, h = lane & 15;
  int s = off[w], e = off[w + 1];
  float acc[8];
#pragma unroll
  for (int j = 0; j < 8; j++) acc[j] = 0.f;
  for (int i0 = s; i0 < e; i0 += 8) {
    int iA = i0 + q, iB = i0 + 4 + q;
    int uA = pool[min(iA, e - 1)], uB = pool[min(iB, e - 1)];
    uint4 a = *(const uint4*)(x + (size_t)uA * 64 + h * 4);
    uint4 b = *(const uint4*)(x + (size_t)uB * 64 + h * 4);
    float sA = (iA < e) ? dinv[uA] : 0.f, sB = (iB < e) ? dinv[uB] : 0.f;
    float fa[8], fb[8];
    unpack8(a, fa); unpack8(b, fb);
#pragma unroll
    for (int j = 0; j < 8; j++) acc[j] = fmaf(fa[j], sA, fmaf(fb[j], sB, acc[j]));
  }
#pragma unroll
  for (int j = 0; j < 8; j++) {
    acc[j] += __shfl_xor(acc[j], 16, 64);
    acc[j] += __shfl_xor(acc[j], 32, 64);
  }
  if (q == 0) {
    float dw = dinv[w];
    uint4 xv = *(const uint4*)(x + (size_t)w * 64 + h * 4);
    float fx[8];
    unpack8(xv, fx);
    uint4 o;
    float r0 = acc[0] * dw + fx[0] * dw * dw, r1 = acc[1] * dw + fx[1] * dw * dw;
    float r2 = acc[2] * dw + fx[2] * dw * dw, r3 = acc[3] * dw + fx[3] * dw * dw;
    float r4 = acc[4] * dw + fx[4] * dw * dw, r5 = acc[5] * dw + fx[5] * dw * dw;
    float r6 = acc[6] * dw + fx[6] * dw * dw, r7 = acc[7] * dw + fx[7] * dw * dw;
    o.x = pack2(r0, r1); o.y = pack2(r2, r3); o.z = pack2(r4, r5); o.w = pack2(r6, r7);
    *(uint4*)(outb + (size_t)w * 64 + h * 4) = o;
  }
}

__global__ __launch_bounds__(256) void sage_agg_mw(const unsigned* __restrict__ x,
                                                   const int* __restrict__ pool,
                                                   const int* __restrict__ off,
                                                   unsigned* __restrict__ outb, int n) {
  __shared__ float psum[3][128];
  int node = blockIdx.x;
  if (node >= n) return;
  int sub = threadIdx.x >> 6, lane = threadIdx.x & 63;
  int q = lane >> 4, h = lane & 15;
  int s = off[node], e = off[node + 1];
  float acc[8];
#pragma unroll
  for (int j = 0; j < 8; j++) acc[j] = 0.f;
  for (int i0 = s + sub * 4; i0 < e; i0 += 16) {
    int idx = i0 + q;
    int u = pool[min(idx, e - 1)];
    uint4 a = *(const uint4*)(x + (size_t)u * 64 + h * 4);
    float sc = (idx < e) ? 1.f : 0.f;
    float fa[8];
    unpack8(a, fa);
#pragma unroll
    for (int j = 0; j < 8; j++) acc[j] = fmaf(fa[j], sc, acc[j]);
  }
#pragma unroll
  for (int j = 0; j < 8; j++) {
    acc[j] += __shfl_xor(acc[j], 16, 64);
    acc[j] += __shfl_xor(acc[j], 32, 64);
  }
  if (sub && q == 0) {
#pragma unroll
    for (int j = 0; j < 8; j++) psum[sub - 1][h * 8 + j] = acc[j];
  }
  __syncthreads();
  if (sub == 0 && q == 0) {
#pragma unroll
    for (int j = 0; j < 8; j++)
      acc[j] += psum[0][h * 8 + j] + psum[1][h * 8 + j] + psum[2][h * 8 + j];
    float inv = (e > s) ? 1.0f / (float)(e - s) : 0.0f;
    uint4 o;
    o.x = pack2(acc[0] * inv, acc[1] * inv);
    o.y = pack2(acc[2] * inv, acc[3] * inv);
    o.z = pack2(acc[4] * inv, acc[5] * inv);
    o.w = pack2(acc[6] * inv, acc[7] * inv);
    *(uint4*)(outb + (size_t)node * 64 + h * 4) = o;
  }
}

// ---------------- MFMA GEMM: out = relu(bias + sum_p A_p @ W_p) ----------------

#define LDA 136

__global__ __launch_bounds__(256) void gemm_mfma(
    const unsigned short* __restrict__ a0, const unsigned short* __restrict__ w0,
    const unsigned short* __restrict__ a1, const unsigned short* __restrict__ w1,
    const unsigned short* __restrict__ a2, const unsigned short* __restrict__ w2,
    const unsigned short* __restrict__ a3, const unsigned short* __restrict__ w3,
    const unsigned short* __restrict__ a4, const unsigned short* __restrict__ w4,
    const float* __restrict__ bias, unsigned short* __restrict__ out, int n) {
  __shared__ __align__(16) unsigned short As[64 * LDA];
  __shared__ __align__(16) unsigned short Ws[128 * LDA];

  int tid = threadIdx.x;
  int w = tid >> 6, lane = tid & 63;
  int q = lane >> 4, c = lane & 15;
  int r0 = blockIdx.x * 64;

  const unsigned short* Ap[5] = {a0, a1, a2, a3, a4};
  const unsigned short* Wp[5] = {w0, w1, w2, w3, w4};

  float bias_v[8];
#pragma unroll
  for (int n0 = 0; n0 < 8; n0++) bias_v[n0] = bias[n0 * 16 + c];

  f32x4 acc[8];
#pragma unroll
  for (int n0 = 0; n0 < 8; n0++) acc[n0] = (f32x4){0.f, 0.f, 0.f, 0.f};

  for (int p = 0; p < 5; p++) {
    if (!Ap[p]) continue;
    __syncthreads();
    for (int j = tid; j < 2048; j += 256) {
      int row = j >> 4, colc = (j & 15) * 8;
      *(uint4*)&Ws[row * LDA + colc] = *(const uint4*)(Wp[p] + row * 128 + colc);
    }
    for (int j = tid; j < 1024; j += 256) {
      int row = j >> 4, colc = (j & 15) * 8;
      uint4 v = make_uint4(0u, 0u, 0u, 0u);
      if (r0 + row < n) v = *(const uint4*)(Ap[p] + (size_t)(r0 + row) * 128 + colc);
      *(uint4*)&As[row * LDA + colc] = v;
    }
    __syncthreads();

    int arow = (w * 16 + c) * LDA;
#pragma unroll
    for (int k0 = 0; k0 < 128; k0 += 32) {
      bf16x8 af = *(const bf16x8*)&As[arow + k0 + q * 8];
#pragma unroll
      for (int n0 = 0; n0 < 8; n0++) {
        bf16x8 bfv = *(const bf16x8*)&Ws[(n0 * 16 + c) * LDA + k0 + q * 8];
        acc[n0] = __builtin_amdgcn_mfma_f32_16x16x32_bf16(af, bfv, acc[n0], 0, 0, 0);
      }
    }
  }

  __syncthreads();
#pragma unroll
  for (int n0 = 0; n0 < 8; n0++) {
#pragma unroll
    for (int reg = 0; reg < 4; reg++) {
      float v = acc[n0][reg] + bias_v[n0];
      v = fmaxf(v, 0.f);
      As[(w * 16 + q * 4 + reg) * LDA + n0 * 16 + c] = f2bf(v);
    }
  }
  __syncthreads();
  for (int j = tid; j < 1024; j += 256) {
    int row = j >> 4, colc = (j & 15) * 8;
    if (r0 + row < n)
      *(uint4*)(out + (size_t)(r0 + row) * 128 + colc) = *(const uint4*)&As[row * LDA + colc];
  }
}

// ---------------- final dot products (4 pairs per wave) ----------------

__global__ void dots_kernel(const unsigned* __restrict__ xs, const unsigned* __restrict__ xm,
                            const unsigned* __restrict__ xr, const int* __restrict__ ls,
                            const int* __restrict__ lm, const int* __restrict__ lr,
                            float* __restrict__ out) {
  int wv = (blockIdx.x * blockDim.x + threadIdx.x) >> 6;
  int lane = threadIdx.x & 63;
  int q = lane >> 4, h = lane & 15;
  int i = wv * 4 + q;
  if (i >= LBL) return;
  int im = lm[i], is = ls[i], ir = lr[i];
  uint4 mv = *(const uint4*)(xm + (size_t)im * 64 + h * 4);
  uint4 sv = *(const uint4*)(xs + (size_t)is * 64 + h * 4);
  uint4 rv = *(const uint4*)(xr + (size_t)ir * 64 + h * 4);
  float fm[8], fs[8], fr[8];
  unpack8(mv, fm); unpack8(sv, fs); unpack8(rv, fr);
  float p1 = 0.f, p2 = 0.f;
#pragma unroll
  for (int j = 0; j < 8; j++) { p1 = fmaf(fs[j], fm[j], p1); p2 = fmaf(fr[j], fm[j], p2); }
#pragma unroll
  for (int m = 1; m < 16; m <<= 1) {
    p1 += __shfl_xor(p1, m, 64);
    p2 += __shfl_xor(p2, m, 64);
  }
  if (h == 0) { out[i] = p1; out[LBL + i] = p2; }
}

// ---------------- host launcher ----------------

extern "C" void kernel_launch(void* const* d_in, const int* in_sizes, int n_in,
                              void* d_out, int out_size, void* d_ws, size_t ws_size,
                              hipStream_t stream) {
  const float* emb_s = (const float*)d_in[0];
  const float* emb_m = (const float*)d_in[1];
  const float* emb_r = (const float*)d_in[2];
  const float* sWl = (const float*)d_in[3];
  const float* sbl = (const float*)d_in[4];
  const float* sWr = (const float*)d_in[5];
  const float* gW  = (const float*)d_in[6];
  const float* gb  = (const float*)d_in[7];
  const int* src_sm  = (const int*)d_in[8];
  const int* dst_sm  = (const int*)d_in[9];
  const int* src_rm  = (const int*)d_in[10];
  const int* dst_rm  = (const int*)d_in[11];
  const int* src_sim = (const int*)d_in[12];
  const int* dst_sim = (const int*)d_in[13];
  const int* lbl_s = (const int*)d_in[14];
  const int* lbl_m = (const int*)d_in[15];
  const int* lbl_r = (const int*)d_in[16];
  float* out = (float*)d_out;

  char* p = (char*)d_ws;
  auto alloc = [&](size_t bytes) -> char* {
    char* r = p;
    p += (bytes + 255) & ~(size_t)255;
    return r;
  };

  int* cnt_base = (int*)alloc(sizeof(int) * CNT_TOTAL);
  int* cnt_si_d = cnt_base + 2 * NMN + NSN + NRN;
  int* cnt_si_s = cnt_si_d + NMN;

  int* off_base = (int*)alloc(sizeof(int) * (CNT_TOTAL + 1));
  int* off_sm  = off_base;
  int* off_ms  = off_sm + NMN;
  int* off_rm  = off_ms + NSN;
  int* off_mr  = off_rm + NMN;
  int* off_si  = off_mr + NRN;
  int* off_si2 = off_si + NMN;

  int* bsum = (int*)alloc(sizeof(int) * 512);
  int* bcur = (int*)alloc(sizeof(int) * 512);
  int* pool = (int*)alloc(sizeof(int) * POOL_TOTAL);

  float* dinv1 = (float*)alloc(sizeof(float) * NMN);
  float* dinv2 = (float*)alloc(sizeof(float) * NMN);

  unsigned* xsb = (unsigned*)alloc(sizeof(unsigned) * (size_t)NSN * 64);
  unsigned* xmb = (unsigned*)alloc(sizeof(unsigned) * (size_t)NMN * 64);
  unsigned* xrb = (unsigned*)alloc(sizeof(unsigned) * (size_t)NRN * 64);
  unsigned* xs0 = (unsigned*)alloc(sizeof(unsigned) * (size_t)NSN * 64);
  unsigned* xs1 = (unsigned*)alloc(sizeof(unsigned) * (size_t)NSN * 64);
  unsigned* xm0 = (unsigned*)alloc(sizeof(unsigned) * (size_t)NMN * 64);
  unsigned* xm1 = (unsigned*)alloc(sizeof(unsigned) * (size_t)NMN * 64);
  unsigned* xr0 = (unsigned*)alloc(sizeof(unsigned) * (size_t)NRN * 64);
  unsigned* xr1 = (unsigned*)alloc(sizeof(unsigned) * (size_t)NRN * 64);
  unsigned* aggA = (unsigned*)alloc(sizeof(unsigned) * (size_t)NMN * 64);
  unsigned* aggB = (unsigned*)alloc(sizeof(unsigned) * (size_t)NMN * 64);
  unsigned* aggC = (unsigned*)alloc(sizeof(unsigned) * (size_t)NMN * 64);
  unsigned* aggD = (unsigned*)alloc(sizeof(unsigned) * (size_t)NMN * 64);

  unsigned short* wt = (unsigned short*)alloc(sizeof(unsigned short) * 18 * 16384);
  float* biasM = (float*)alloc(sizeof(float) * 2 * 128);

  // stage aliases aggA..aggD (4 x 25.6MB contiguous = 102.4MB >= 80MB needed);
  // fill completes before any agg uses these buffers (stream-ordered).
  int* stage = (int*)aggA;

  auto WT = [&](int l, int slot) -> const unsigned short* {
    return wt + (((size_t)l * 9 + slot) << 14);
  };

  // ---- CSR build ----
  zero_int<<<(CNT_TOTAL + 255) / 256, 256, 0, stream>>>(cnt_base, CNT_TOTAL);
  hist2<<<(ESM + 255) / 256, 256, 0, stream>>>(src_sm, dst_sm, ESM, cnt_base, cnt_base + NMN);
  hist2<<<(ERM + 255) / 256, 256, 0, stream>>>(src_rm, dst_rm, ERM, cnt_base + NMN + NSN,
                                               cnt_base + 2 * NMN + NSN);
  hist2<<<(ESIM + 255) / 256, 256, 0, stream>>>(src_sim, dst_sim, ESIM, cnt_si_d, cnt_si_s);

  const int NB = (CNT_TOTAL + 1023) / 1024;  // 398
  scan_partial<<<NB, 256, 0, stream>>>(cnt_base, CNT_TOTAL, bsum);
  scan_bsum<<<1, 512, 0, stream>>>(bsum, NB, off_base + CNT_TOTAL);
  scan_write<<<NB, 256, 0, stream>>>(cnt_base, CNT_TOTAL, bsum, off_base);

  // ---- two-phase fill ----
  init_bcur<<<2, 256, 0, stream>>>(off_base, bcur);
  multisplit<10, 98, 6, 79><<<(ESM + 2047) / 2048, 256, 0, stream>>>(
      src_sm, dst_sm, ESM, bcur, 0, stage);
  multisplit<11, 49, 5, 63><<<(ERM + 2047) / 2048, 256, 0, stream>>>(
      src_rm, dst_rm, ERM, bcur, 177, stage);
  multisplit<10, 98, 10, 98><<<(ESIM + 2047) / 2048, 256, 0, stream>>>(
      src_sim, dst_sim, ESIM, bcur, 289, stage);
  zero_int<<<(CNT_TOTAL + 255) / 256, 256, 0, stream>>>(cnt_base, CNT_TOTAL);  // cursors
  scatter_bucket<<<NBTOT, 256, 0, stream>>>(stage, off_base, cnt_base, pool);

  compute_dinv<<<(NMN + 255) / 256, 256, 0, stream>>>(off_si, off_si2, dinv1, dinv2, NMN);
  trans_weights<<<(18 * 16384 + 255) / 256, 256, 0, stream>>>(sWl, sWr, gW, wt);
  prep_bias<<<1, 256, 0, stream>>>(sbl, gb, biasM);
  cast_all<<<(NMN * 64 + 255) / 256, 256, 0, stream>>>((const float2*)emb_s, (const float2*)emb_m,
                                                       (const float2*)emb_r, xsb, xmb, xrb);

  for (int l = 0; l < 2; ++l) {
    const unsigned* xs_c = l ? xs0 : xsb;
    const unsigned* xm_c = l ? xm0 : xmb;
    const unsigned* xr_c = l ? xr0 : xrb;
    unsigned* xs_n = l ? xs1 : xs0;
    unsigned* xm_n = l ? xm1 : xm0;
    unsigned* xr_n = l ? xr1 : xr0;

    sage_agg<<<(NMN + 3) / 4, 256, 0, stream>>>(xs_c, pool, off_sm, aggA, NMN);
    sage_agg<<<(NMN + 3) / 4, 256, 0, stream>>>(xr_c, pool, off_rm, aggB, NMN);
    gcn_agg<<<(NMN + 3) / 4, 256, 0, stream>>>(xm_c, pool, off_si, dinv1, aggC, NMN);
    gcn_agg<<<(NMN + 3) / 4, 256, 0, stream>>>(xm_c, pool, off_si2, dinv2, aggD, NMN);
    gemm_mfma<<<(NMN + 63) / 64, 256, 0, stream>>>(
        (const unsigned short*)aggA, WT(l, 0), (const unsigned short*)aggB, WT(l, 2),
        (const unsigned short*)aggC, WT(l, 4), (const unsigned short*)aggD, WT(l, 5),
        (const unsigned short*)xm_c, WT(l, 6), biasM + l * 128,
        (unsigned short*)xm_n, NMN);

    sage_agg_mw<<<NSN, 256, 0, stream>>>(xm_c, pool, off_ms, aggA, NSN);
    gemm_mfma<<<(NSN + 63) / 64, 256, 0, stream>>>(
        (const unsigned short*)aggA, WT(l, 1), (const unsigned short*)xs_c, WT(l, 7),
        nullptr, nullptr, nullptr, nullptr, nullptr, nullptr,
        sbl + (l * 4 + 1) * 128, (unsigned short*)xs_n, NSN);

    sage_agg_mw<<<NRN, 256, 0, stream>>>(xm_c, pool, off_mr, aggB, NRN);
    gemm_mfma<<<(NRN + 63) / 64, 256, 0, stream>>>(
        (const unsigned short*)aggB, WT(l, 3), (const unsigned short*)xr_c, WT(l, 8),
        nullptr, nullptr, nullptr, nullptr, nullptr, nullptr,
        sbl + (l * 4 + 3) * 128, (unsigned short*)xr_n, NRN);
  }

  dots_kernel<<<(LBL * 16 + 255) / 256, 256, 0, stream>>>(xs1, xm1, xr1, lbl_s, lbl_m, lbl_r, out);
}

// Round 7
// 1649.292 us; speedup vs baseline: 1.4292x; 1.2048x over previous
//
#include <hip/hip_runtime.h>
#include <hip/hip_bf16.h>

#define NSN 5000
#define NMN 100000
#define NRN 2000
#define HDIM 128
#define ESM 2000000
#define ERM 1000000
#define ESIM 2000000
#define LBL 500000

#define CNT_TOTAL (4 * NMN + NSN + NRN)  // 407000
#define POOL_TOTAL (2 * ESM + 2 * ERM + 2 * ESIM)  // 10M
#define NBTOT 1222
#define WCAP 14336   // LDS window capacity (ints) = 56 KB
#define MAXNODES 512

typedef short bf16x8 __attribute__((ext_vector_type(8)));
typedef float f32x4 __attribute__((ext_vector_type(4)));

__device__ __forceinline__ unsigned short f2bf(float f) {
  unsigned u = __float_as_uint(f);
  unsigned r = (u + 0x7fffu + ((u >> 16) & 1u)) >> 16;  // RNE
  return (unsigned short)r;
}
__device__ __forceinline__ float bf_lo(unsigned v) { return __uint_as_float(v << 16); }
__device__ __forceinline__ float bf_hi(unsigned v) { return __uint_as_float(v & 0xffff0000u); }
__device__ __forceinline__ unsigned pack2(float x, float y) {
  return (unsigned)f2bf(x) | ((unsigned)f2bf(y) << 16);
}
__device__ __forceinline__ void unpack8(uint4 v, float* f) {
  f[0] = bf_lo(v.x); f[1] = bf_hi(v.x);
  f[2] = bf_lo(v.y); f[3] = bf_hi(v.y);
  f[4] = bf_lo(v.z); f[5] = bf_hi(v.z);
  f[6] = bf_lo(v.w); f[7] = bf_hi(v.w);
}

// ---------------- CSR build ----------------

__global__ void zero_int(int* __restrict__ p, int n) {
  int i = blockIdx.x * blockDim.x + threadIdx.x;
  if (i < n) p[i] = 0;
}

__global__ void hist2(const int* __restrict__ a, const int* __restrict__ b, int n,
                      int* __restrict__ cntA, int* __restrict__ cntB) {
  int i = blockIdx.x * blockDim.x + threadIdx.x;
  if (i < n) {
    atomicAdd(&cntA[b[i]], 1);  // dst-indexed
    atomicAdd(&cntB[a[i]], 1);  // src-indexed
  }
}

__global__ void scan_partial(const int* __restrict__ cnt, int n, int* __restrict__ bsum) {
  __shared__ int sdata[256];
  int b = blockIdx.x, t = threadIdx.x;
  int base = b * 1024;
  int s = 0;
  for (int j = t; j < 1024; j += 256) { int i = base + j; if (i < n) s += cnt[i]; }
  sdata[t] = s; __syncthreads();
  for (int o = 128; o > 0; o >>= 1) { if (t < o) sdata[t] += sdata[t + o]; __syncthreads(); }
  if (t == 0) bsum[b] = sdata[0];
}

__global__ void scan_bsum(int* __restrict__ bsum, int nb, int* __restrict__ off_end) {
  __shared__ int buf[512];
  int t = threadIdx.x;  // 512 threads
  int v = (t < nb) ? bsum[t] : 0;
  buf[t] = v; __syncthreads();
  for (int o = 1; o < 512; o <<= 1) {
    int a = (t >= o) ? buf[t - o] : 0;
    __syncthreads();
    buf[t] += a;
    __syncthreads();
  }
  if (t < nb) bsum[t] = buf[t] - v;     // exclusive
  if (t == 511) *off_end = buf[511];    // grand total
}

__global__ void scan_write(const int* __restrict__ cnt, int n, const int* __restrict__ bsum,
                           int* __restrict__ off) {
  __shared__ int buf[256];
  int b = blockIdx.x, t = threadIdx.x;
  int base = b * 1024 + t * 4;
  int v0 = 0, v1 = 0, v2 = 0, v3 = 0;
  if (base + 0 < n) v0 = cnt[base + 0];
  if (base + 1 < n) v1 = cnt[base + 1];
  if (base + 2 < n) v2 = cnt[base + 2];
  if (base + 3 < n) v3 = cnt[base + 3];
  int s = v0 + v1 + v2 + v3;
  buf[t] = s; __syncthreads();
  for (int o = 1; o < 256; o <<= 1) {
    int a = (t >= o) ? buf[t - o] : 0;
    __syncthreads();
    buf[t] += a;
    __syncthreads();
  }
  int run = buf[t] - s + bsum[b];
  if (base + 0 < n) off[base + 0] = run; run += v0;
  if (base + 1 < n) off[base + 1] = run; run += v1;
  if (base + 2 < n) off[base + 2] = run; run += v2;
  if (base + 3 < n) off[base + 3] = run;
}

// Bucket table (node-range buckets sized so pool windows fit LDS):
// sm fwd: 0..195    (NM,>>9)   sm rev: 196..508  (NS,>>4)
// rm fwd: 509..704  (NM,>>9)   rm rev: 705..829  (NR,>>4)
// si fwd: 830..1025 (NM,>>9)   si rev: 1026..1221(NM,>>9)
struct BInfo { int g; int ns; int ne; };
__device__ __forceinline__ BInfo binfo(int id) {
  BInfo bi;
  if (id < 196)       { int k = id;        bi.g = 0;                   bi.ns = k << 9; bi.ne = min(bi.ns + 512, NMN); }
  else if (id < 509)  { int k = id - 196;  bi.g = NMN;                 bi.ns = k << 4; bi.ne = min(bi.ns + 16,  NSN); }
  else if (id < 705)  { int k = id - 509;  bi.g = NMN + NSN;           bi.ns = k << 9; bi.ne = min(bi.ns + 512, NMN); }
  else if (id < 830)  { int k = id - 705;  bi.g = 2 * NMN + NSN;       bi.ns = k << 4; bi.ne = min(bi.ns + 16,  NRN); }
  else if (id < 1026) { int k = id - 830;  bi.g = 2 * NMN + NSN + NRN; bi.ns = k << 9; bi.ne = min(bi.ns + 512, NMN); }
  else                { int k = id - 1026; bi.g = 3 * NMN + NSN + NRN; bi.ns = k << 9; bi.ne = min(bi.ns + 512, NMN); }
  return bi;
}

__global__ void init_bcur(const int* __restrict__ offG, int* __restrict__ bcur) {
  int id = blockIdx.x * blockDim.x + threadIdx.x;
  if (id < NBTOT) { BInfo bi = binfo(id); bcur[id] = offG[bi.g + bi.ns]; }
}

// Phase A: multisplit edges into bucket-partitioned (target,payload) staging.
// 4096-edge tile per block; LDS hist -> one global atomic per (tile,bucket)
// -> staged pairs land in per-tile contiguous runs (~21 pairs = 168 B).
template <int SHF, int NBF, int SHR, int NBR>
__global__ __launch_bounds__(256) void multisplit(
    const int* __restrict__ a, const int* __restrict__ b, int n,
    int* __restrict__ bcur, int bb, int* __restrict__ stage) {
  __shared__ int hist[NBF + NBR];
  __shared__ int gpos[NBF + NBR];
  int tid = threadIdx.x;
  int base = blockIdx.x * 4096;
  for (int k = tid; k < NBF + NBR; k += 256) hist[k] = 0;
  __syncthreads();
  int dv[16], sv[16];
#pragma unroll
  for (int j = 0; j < 16; j++) {
    int idx = base + j * 256 + tid;
    if (idx < n) {
      sv[j] = a[idx]; dv[j] = b[idx];
      atomicAdd(&hist[dv[j] >> SHF], 1);
      atomicAdd(&hist[NBF + (sv[j] >> SHR)], 1);
    } else {
      dv[j] = -1;
    }
  }
  __syncthreads();
  for (int k = tid; k < NBF + NBR; k += 256) {
    int c = hist[k];
    gpos[k] = c ? atomicAdd(&bcur[bb + k], c) : 0;
  }
  __syncthreads();
#pragma unroll
  for (int j = 0; j < 16; j++) {
    if (dv[j] >= 0) {
      int s1 = atomicAdd(&gpos[dv[j] >> SHF], 1);
      stage[2 * s1] = dv[j]; stage[2 * s1 + 1] = sv[j];
      int s2 = atomicAdd(&gpos[NBF + (sv[j] >> SHR)], 1);
      stage[2 * s2] = sv[j]; stage[2 * s2 + 1] = dv[j];
    }
  }
}

// Phase B: one block per bucket; scatter into an LDS-resident pool window
// (private to the block -> zero global write amplification), then stream the
// window out sequentially. Fallback to global-cursor scatter if a window ever
// exceeds LDS capacity (correctness never depends on bucket statistics).
__global__ __launch_bounds__(256) void scatter_bucket(
    const int* __restrict__ stage, const int* __restrict__ offG,
    int* __restrict__ cur, int* __restrict__ pool) {
  __shared__ int win[WCAP];
  __shared__ int curs[MAXNODES];
  BInfo bi = binfo(blockIdx.x);
  int s0 = offG[bi.g + bi.ns], s1 = offG[bi.g + bi.ne];
  int sz = s1 - s0;
  int nn = bi.ne - bi.ns;
  if (sz <= WCAP) {
    for (int k = threadIdx.x; k < nn; k += 256)
      curs[k] = offG[bi.g + bi.ns + k] - s0;
    __syncthreads();
    for (int k = s0 + (int)threadIdx.x; k < s1; k += 256) {
      int d = stage[2 * k], s_ = stage[2 * k + 1];
      int slot = atomicAdd(&curs[d - bi.ns], 1);
      win[slot] = s_;
    }
    __syncthreads();
    for (int k = threadIdx.x; k < sz; k += 256) pool[s0 + k] = win[k];
  } else {
    for (int k = s0 + (int)threadIdx.x; k < s1; k += 256) {
      int d = stage[2 * k], s_ = stage[2 * k + 1];
      int slot = atomicAdd(&cur[bi.g + d], 1);
      pool[offG[bi.g + d] + slot] = s_;
    }
  }
}

__global__ void compute_dinv(const int* __restrict__ off1, const int* __restrict__ off2,
                             float* __restrict__ dinv1, float* __restrict__ dinv2, int n) {
  int v = blockIdx.x * blockDim.x + threadIdx.x;
  if (v < n) {
    dinv1[v] = rsqrtf((float)(off1[v + 1] - off1[v] + 1));
    dinv2[v] = rsqrtf((float)(off2[v + 1] - off2[v] + 1));
  }
}

// bf16 transposed weights wt[(l*9+slot)][n][k], slots:
// 0..3 = sage_Wl rel0..3; 4,5 = gcn_W; 6 = Wr0+Wr2; 7 = Wr1; 8 = Wr3
__global__ void trans_weights(const float* __restrict__ sWl, const float* __restrict__ sWr,
                              const float* __restrict__ gW, unsigned short* __restrict__ wt) {
  int i = blockIdx.x * blockDim.x + threadIdx.x;
  if (i >= 18 * 16384) return;
  int mat = i >> 14, l = mat / 9, slot = mat % 9;
  int idx = i & 16383, nn = idx >> 7, kk = idx & 127;
  int s_ = kk * 128 + nn;  // source [k][n] row-major
  float v;
  if (slot < 4)      v = sWl[((l * 4 + slot) << 14) + s_];
  else if (slot < 6) v = gW[((l * 2 + (slot - 4)) << 14) + s_];
  else if (slot == 6) v = sWr[((l * 4 + 0) << 14) + s_] + sWr[((l * 4 + 2) << 14) + s_];
  else if (slot == 7) v = sWr[((l * 4 + 1) << 14) + s_];
  else                v = sWr[((l * 4 + 3) << 14) + s_];
  wt[i] = f2bf(v);
}

__global__ void prep_bias(const float* __restrict__ sbl, const float* __restrict__ gb,
                          float* __restrict__ biasM) {
  int i = threadIdx.x;  // 256 threads
  int l = i >> 7, j = i & 127;
  biasM[i] = sbl[(l * 4 + 0) * 128 + j] + sbl[(l * 4 + 2) * 128 + j] +
             gb[(l * 2 + 0) * 128 + j] + gb[(l * 2 + 1) * 128 + j];
}

__global__ void cast_all(const float2* __restrict__ es, const float2* __restrict__ em,
                         const float2* __restrict__ er, unsigned* __restrict__ os,
                         unsigned* __restrict__ om, unsigned* __restrict__ orr) {
  int i = blockIdx.x * blockDim.x + threadIdx.x;
  if (i < NSN * 64) { float2 v = es[i]; os[i] = pack2(v.x, v.y); }
  if (i < NMN * 64) { float2 v = em[i]; om[i] = pack2(v.x, v.y); }
  if (i < NRN * 64) { float2 v = er[i]; orr[i] = pack2(v.x, v.y); }
}

// ---------------- aggregation (quarter-wave uint4 gathers) ----------------

__global__ void sage_agg(const unsigned* __restrict__ x, const int* __restrict__ pool,
                         const int* __restrict__ off, unsigned* __restrict__ outb, int n) {
  int w = (blockIdx.x * blockDim.x + threadIdx.x) >> 6;
  if (w >= n) return;
  int lane = threadIdx.x & 63;
  int q = lane >> 4, h = lane & 15;
  int s = off[w], e = off[w + 1];
  float acc[8];
#pragma unroll
  for (int j = 0; j < 8; j++) acc[j] = 0.f;
  for (int i0 = s; i0 < e; i0 += 8) {
    int iA = i0 + q, iB = i0 + 4 + q;
    int uA = pool[min(iA, e - 1)], uB = pool[min(iB, e - 1)];
    uint4 a = *(const uint4*)(x + (size_t)uA * 64 + h * 4);
    uint4 b = *(const uint4*)(x + (size_t)uB * 64 + h * 4);
    float sA = (iA < e) ? 1.f : 0.f, sB = (iB < e) ? 1.f : 0.f;
    float fa[8], fb[8];
    unpack8(a, fa); unpack8(b, fb);
#pragma unroll
    for (int j = 0; j < 8; j++) acc[j] = fmaf(fa[j], sA, fmaf(fb[j], sB, acc[j]));
  }
#pragma unroll
  for (int j = 0; j < 8; j++) {
    acc[j] += __shfl_xor(acc[j], 16, 64);
    acc[j] += __shfl_xor(acc[j], 32, 64);
  }
  if (q == 0) {
    float inv = (e > s) ? 1.0f / (float)(e - s) : 0.0f;
    uint4 o;
    o.x = pack2(acc[0] * inv, acc[1] * inv);
    o.y = pack2(acc[2] * inv, acc[3] * inv);
    o.z = pack2(acc[4] * inv, acc[5] * inv);
    o.w = pack2(acc[6] * inv, acc[7] * inv);
    *(uint4*)(outb + (size_t)w * 64 + h * 4) = o;
  }
}

__global__ void gcn_agg(const unsigned* __restrict__ x, const int* __restrict__ pool,
                        const int* __restrict__ off, const float* __restrict__ dinv,
                        unsigned* __restrict__ outb, int n) {
  int w = (blockIdx.x * blockDim.x + threadIdx.x) >> 6;
  if (w >= n) return;
  int lane = threadIdx.x & 63;
  int q = lane >> 4, h = lane & 15;
  int s = off[w], e = off[w + 1];
  float acc[8];
#pragma unroll
  for (int j = 0; j < 8; j++) acc[j] = 0.f;
  for (int i0 = s; i0 < e; i0 += 8) {
    int iA = i0 + q, iB = i0 + 4 + q;
    int uA = pool[min(iA, e - 1)], uB = pool[min(iB, e - 1)];
    uint4 a = *(const uint4*)(x + (size_t)uA * 64 + h * 4);
    uint4 b = *(const uint4*)(x + (size_t)uB * 64 + h * 4);
    float sA = (iA < e) ? dinv[uA] : 0.f, sB = (iB < e) ? dinv[uB] : 0.f;
    float fa[8], fb[8];
    unpack8(a, fa); unpack8(b, fb);
#pragma unroll
    for (int j = 0; j < 8; j++) acc[j] = fmaf(fa[j], sA, fmaf(fb[j], sB, acc[j]));
  }
#pragma unroll
  for (int j = 0; j < 8; j++) {
    acc[j] += __shfl_xor(acc[j], 16, 64);
    acc[j] += __shfl_xor(acc[j], 32, 64);
  }
  if (q == 0) {
    float dw = dinv[w];
    uint4 xv = *(const uint4*)(x + (size_t)w * 64 + h * 4);
    float fx[8];
    unpack8(xv, fx);
    uint4 o;
    float r0 = acc[0] * dw + fx[0] * dw * dw, r1 = acc[1] * dw + fx[1] * dw * dw;
    float r2 = acc[2] * dw + fx[2] * dw * dw, r3 = acc[3] * dw + fx[3] * dw * dw;
    float r4 = acc[4] * dw + fx[4] * dw * dw, r5 = acc[5] * dw + fx[5] * dw * dw;
    float r6 = acc[6] * dw + fx[6] * dw * dw, r7 = acc[7] * dw + fx[7] * dw * dw;
    o.x = pack2(r0, r1); o.y = pack2(r2, r3); o.z = pack2(r4, r5); o.w = pack2(r6, r7);
    *(uint4*)(outb + (size_t)w * 64 + h * 4) = o;
  }
}

__global__ __launch_bounds__(256) void sage_agg_mw(const unsigned* __restrict__ x,
                                                   const int* __restrict__ pool,
                                                   const int* __restrict__ off,
                                                   unsigned* __restrict__ outb, int n) {
  __shared__ float psum[3][128];
  int node = blockIdx.x;
  if (node >= n) return;
  int sub = threadIdx.x >> 6, lane = threadIdx.x & 63;
  int q = lane >> 4, h = lane & 15;
  int s = off[node], e = off[node + 1];
  float acc[8];
#pragma unroll
  for (int j = 0; j < 8; j++) acc[j] = 0.f;
  for (int i0 = s + sub * 4; i0 < e; i0 += 16) {
    int idx = i0 + q;
    int u = pool[min(idx, e - 1)];
    uint4 a = *(const uint4*)(x + (size_t)u * 64 + h * 4);
    float sc = (idx < e) ? 1.f : 0.f;
    float fa[8];
    unpack8(a, fa);
#pragma unroll
    for (int j = 0; j < 8; j++) acc[j] = fmaf(fa[j], sc, acc[j]);
  }
#pragma unroll
  for (int j = 0; j < 8; j++) {
    acc[j] += __shfl_xor(acc[j], 16, 64);
    acc[j] += __shfl_xor(acc[j], 32, 64);
  }
  if (sub && q == 0) {
#pragma unroll
    for (int j = 0; j < 8; j++) psum[sub - 1][h * 8 + j] = acc[j];
  }
  __syncthreads();
  if (sub == 0 && q == 0) {
#pragma unroll
    for (int j = 0; j < 8; j++)
      acc[j] += psum[0][h * 8 + j] + psum[1][h * 8 + j] + psum[2][h * 8 + j];
    float inv = (e > s) ? 1.0f / (float)(e - s) : 0.0f;
    uint4 o;
    o.x = pack2(acc[0] * inv, acc[1] * inv);
    o.y = pack2(acc[2] * inv, acc[3] * inv);
    o.z = pack2(acc[4] * inv, acc[5] * inv);
    o.w = pack2(acc[6] * inv, acc[7] * inv);
    *(uint4*)(outb + (size_t)node * 64 + h * 4) = o;
  }
}

// ---------------- MFMA GEMM: out = relu(bias + sum_p A_p @ W_p) ----------------

#define LDA 136

__global__ __launch_bounds__(256) void gemm_mfma(
    const unsigned short* __restrict__ a0, const unsigned short* __restrict__ w0,
    const unsigned short* __restrict__ a1, const unsigned short* __restrict__ w1,
    const unsigned short* __restrict__ a2, const unsigned short* __restrict__ w2,
    const unsigned short* __restrict__ a3, const unsigned short* __restrict__ w3,
    const unsigned short* __restrict__ a4, const unsigned short* __restrict__ w4,
    const float* __restrict__ bias, unsigned short* __restrict__ out, int n) {
  __shared__ __align__(16) unsigned short As[64 * LDA];
  __shared__ __align__(16) unsigned short Ws[128 * LDA];

  int tid = threadIdx.x;
  int w = tid >> 6, lane = tid & 63;
  int q = lane >> 4, c = lane & 15;
  int r0 = blockIdx.x * 64;

  const unsigned short* Ap[5] = {a0, a1, a2, a3, a4};
  const unsigned short* Wp[5] = {w0, w1, w2, w3, w4};

  float bias_v[8];
#pragma unroll
  for (int n0 = 0; n0 < 8; n0++) bias_v[n0] = bias[n0 * 16 + c];

  f32x4 acc[8];
#pragma unroll
  for (int n0 = 0; n0 < 8; n0++) acc[n0] = (f32x4){0.f, 0.f, 0.f, 0.f};

  for (int p = 0; p < 5; p++) {
    if (!Ap[p]) continue;
    __syncthreads();
    for (int j = tid; j < 2048; j += 256) {
      int row = j >> 4, colc = (j & 15) * 8;
      *(uint4*)&Ws[row * LDA + colc] = *(const uint4*)(Wp[p] + row * 128 + colc);
    }
    for (int j = tid; j < 1024; j += 256) {
      int row = j >> 4, colc = (j & 15) * 8;
      uint4 v = make_uint4(0u, 0u, 0u, 0u);
      if (r0 + row < n) v = *(const uint4*)(Ap[p] + (size_t)(r0 + row) * 128 + colc);
      *(uint4*)&As[row * LDA + colc] = v;
    }
    __syncthreads();

    int arow = (w * 16 + c) * LDA;
#pragma unroll
    for (int k0 = 0; k0 < 128; k0 += 32) {
      bf16x8 af = *(const bf16x8*)&As[arow + k0 + q * 8];
#pragma unroll
      for (int n0 = 0; n0 < 8; n0++) {
        bf16x8 bfv = *(const bf16x8*)&Ws[(n0 * 16 + c) * LDA + k0 + q * 8];
        acc[n0] = __builtin_amdgcn_mfma_f32_16x16x32_bf16(af, bfv, acc[n0], 0, 0, 0);
      }
    }
  }

  __syncthreads();
#pragma unroll
  for (int n0 = 0; n0 < 8; n0++) {
#pragma unroll
    for (int reg = 0; reg < 4; reg++) {
      float v = acc[n0][reg] + bias_v[n0];
      v = fmaxf(v, 0.f);
      As[(w * 16 + q * 4 + reg) * LDA + n0 * 16 + c] = f2bf(v);
    }
  }
  __syncthreads();
  for (int j = tid; j < 1024; j += 256) {
    int row = j >> 4, colc = (j & 15) * 8;
    if (r0 + row < n)
      *(uint4*)(out + (size_t)(r0 + row) * 128 + colc) = *(const uint4*)&As[row * LDA + colc];
  }
}

// ---------------- final dot products (4 pairs per wave) ----------------

__global__ void dots_kernel(const unsigned* __restrict__ xs, const unsigned* __restrict__ xm,
                            const unsigned* __restrict__ xr, const int* __restrict__ ls,
                            const int* __restrict__ lm, const int* __restrict__ lr,
                            float* __restrict__ out) {
  int wv = (blockIdx.x * blockDim.x + threadIdx.x) >> 6;
  int lane = threadIdx.x & 63;
  int q = lane >> 4, h = lane & 15;
  int i = wv * 4 + q;
  if (i >= LBL) return;
  int im = lm[i], is = ls[i], ir = lr[i];
  uint4 mv = *(const uint4*)(xm + (size_t)im * 64 + h * 4);
  uint4 sv = *(const uint4*)(xs + (size_t)is * 64 + h * 4);
  uint4 rv = *(const uint4*)(xr + (size_t)ir * 64 + h * 4);
  float fm[8], fs[8], fr[8];
  unpack8(mv, fm); unpack8(sv, fs); unpack8(rv, fr);
  float p1 = 0.f, p2 = 0.f;
#pragma unroll
  for (int j = 0; j < 8; j++) { p1 = fmaf(fs[j], fm[j], p1); p2 = fmaf(fr[j], fm[j], p2); }
#pragma unroll
  for (int m = 1; m < 16; m <<= 1) {
    p1 += __shfl_xor(p1, m, 64);
    p2 += __shfl_xor(p2, m, 64);
  }
  if (h == 0) { out[i] = p1; out[LBL + i] = p2; }
}

// ---------------- host launcher ----------------

extern "C" void kernel_launch(void* const* d_in, const int* in_sizes, int n_in,
                              void* d_out, int out_size, void* d_ws, size_t ws_size,
                              hipStream_t stream) {
  const float* emb_s = (const float*)d_in[0];
  const float* emb_m = (const float*)d_in[1];
  const float* emb_r = (const float*)d_in[2];
  const float* sWl = (const float*)d_in[3];
  const float* sbl = (const float*)d_in[4];
  const float* sWr = (const float*)d_in[5];
  const float* gW  = (const float*)d_in[6];
  const float* gb  = (const float*)d_in[7];
  const int* src_sm  = (const int*)d_in[8];
  const int* dst_sm  = (const int*)d_in[9];
  const int* src_rm  = (const int*)d_in[10];
  const int* dst_rm  = (const int*)d_in[11];
  const int* src_sim = (const int*)d_in[12];
  const int* dst_sim = (const int*)d_in[13];
  const int* lbl_s = (const int*)d_in[14];
  const int* lbl_m = (const int*)d_in[15];
  const int* lbl_r = (const int*)d_in[16];
  float* out = (float*)d_out;

  char* p = (char*)d_ws;
  auto alloc = [&](size_t bytes) -> char* {
    char* r = p;
    p += (bytes + 255) & ~(size_t)255;
    return r;
  };

  int* cnt_base = (int*)alloc(sizeof(int) * CNT_TOTAL);
  int* cnt_si_d = cnt_base + 2 * NMN + NSN + NRN;
  int* cnt_si_s = cnt_si_d + NMN;

  int* off_base = (int*)alloc(sizeof(int) * (CNT_TOTAL + 1));
  int* off_sm  = off_base;
  int* off_ms  = off_sm + NMN;
  int* off_rm  = off_ms + NSN;
  int* off_mr  = off_rm + NMN;
  int* off_si  = off_mr + NRN;
  int* off_si2 = off_si + NMN;

  int* bsum = (int*)alloc(sizeof(int) * 512);
  int* bcur = (int*)alloc(sizeof(int) * 1280);
  int* pool = (int*)alloc(sizeof(int) * POOL_TOTAL);

  float* dinv1 = (float*)alloc(sizeof(float) * NMN);
  float* dinv2 = (float*)alloc(sizeof(float) * NMN);

  unsigned* xsb = (unsigned*)alloc(sizeof(unsigned) * (size_t)NSN * 64);
  unsigned* xmb = (unsigned*)alloc(sizeof(unsigned) * (size_t)NMN * 64);
  unsigned* xrb = (unsigned*)alloc(sizeof(unsigned) * (size_t)NRN * 64);
  unsigned* xs0 = (unsigned*)alloc(sizeof(unsigned) * (size_t)NSN * 64);
  unsigned* xs1 = (unsigned*)alloc(sizeof(unsigned) * (size_t)NSN * 64);
  unsigned* xm0 = (unsigned*)alloc(sizeof(unsigned) * (size_t)NMN * 64);
  unsigned* xm1 = (unsigned*)alloc(sizeof(unsigned) * (size_t)NMN * 64);
  unsigned* xr0 = (unsigned*)alloc(sizeof(unsigned) * (size_t)NRN * 64);
  unsigned* xr1 = (unsigned*)alloc(sizeof(unsigned) * (size_t)NRN * 64);
  unsigned* aggA = (unsigned*)alloc(sizeof(unsigned) * (size_t)NMN * 64);
  unsigned* aggB = (unsigned*)alloc(sizeof(unsigned) * (size_t)NMN * 64);
  unsigned* aggC = (unsigned*)alloc(sizeof(unsigned) * (size_t)NMN * 64);
  unsigned* aggD = (unsigned*)alloc(sizeof(unsigned) * (size_t)NMN * 64);

  unsigned short* wt = (unsigned short*)alloc(sizeof(unsigned short) * 18 * 16384);
  float* biasM = (float*)alloc(sizeof(float) * 2 * 128);

  // stage aliases aggA..aggD (4 x 25.6MB contiguous = 102.4MB >= 80MB needed);
  // fill completes before any agg uses these buffers (stream-ordered).
  int* stage = (int*)aggA;

  auto WT = [&](int l, int slot) -> const unsigned short* {
    return wt + (((size_t)l * 9 + slot) << 14);
  };

  // ---- CSR build ----
  zero_int<<<(CNT_TOTAL + 255) / 256, 256, 0, stream>>>(cnt_base, CNT_TOTAL);
  hist2<<<(ESM + 255) / 256, 256, 0, stream>>>(src_sm, dst_sm, ESM, cnt_base, cnt_base + NMN);
  hist2<<<(ERM + 255) / 256, 256, 0, stream>>>(src_rm, dst_rm, ERM, cnt_base + NMN + NSN,
                                               cnt_base + 2 * NMN + NSN);
  hist2<<<(ESIM + 255) / 256, 256, 0, stream>>>(src_sim, dst_sim, ESIM, cnt_si_d, cnt_si_s);

  const int NB = (CNT_TOTAL + 1023) / 1024;  // 398
  scan_partial<<<NB, 256, 0, stream>>>(cnt_base, CNT_TOTAL, bsum);
  scan_bsum<<<1, 512, 0, stream>>>(bsum, NB, off_base + CNT_TOTAL);
  scan_write<<<NB, 256, 0, stream>>>(cnt_base, CNT_TOTAL, bsum, off_base);

  // ---- two-phase fill ----
  init_bcur<<<(NBTOT + 255) / 256, 256, 0, stream>>>(off_base, bcur);
  multisplit<9, 196, 4, 313><<<(ESM + 4095) / 4096, 256, 0, stream>>>(
      src_sm, dst_sm, ESM, bcur, 0, stage);
  multisplit<9, 196, 4, 125><<<(ERM + 4095) / 4096, 256, 0, stream>>>(
      src_rm, dst_rm, ERM, bcur, 509, stage);
  multisplit<9, 196, 9, 196><<<(ESIM + 4095) / 4096, 256, 0, stream>>>(
      src_sim, dst_sim, ESIM, bcur, 830, stage);
  zero_int<<<(CNT_TOTAL + 255) / 256, 256, 0, stream>>>(cnt_base, CNT_TOTAL);  // fallback cursors
  scatter_bucket<<<NBTOT, 256, 0, stream>>>(stage, off_base, cnt_base, pool);

  compute_dinv<<<(NMN + 255) / 256, 256, 0, stream>>>(off_si, off_si2, dinv1, dinv2, NMN);
  trans_weights<<<(18 * 16384 + 255) / 256, 256, 0, stream>>>(sWl, sWr, gW, wt);
  prep_bias<<<1, 256, 0, stream>>>(sbl, gb, biasM);
  cast_all<<<(NMN * 64 + 255) / 256, 256, 0, stream>>>((const float2*)emb_s, (const float2*)emb_m,
                                                       (const float2*)emb_r, xsb, xmb, xrb);

  for (int l = 0; l < 2; ++l) {
    const unsigned* xs_c = l ? xs0 : xsb;
    const unsigned* xm_c = l ? xm0 : xmb;
    const unsigned* xr_c = l ? xr0 : xrb;
    unsigned* xs_n = l ? xs1 : xs0;
    unsigned* xm_n = l ? xm1 : xm0;
    unsigned* xr_n = l ? xr1 : xr0;

    sage_agg<<<(NMN + 3) / 4, 256, 0, stream>>>(xs_c, pool, off_sm, aggA, NMN);
    sage_agg<<<(NMN + 3) / 4, 256, 0, stream>>>(xr_c, pool, off_rm, aggB, NMN);
    gcn_agg<<<(NMN + 3) / 4, 256, 0, stream>>>(xm_c, pool, off_si, dinv1, aggC, NMN);
    gcn_agg<<<(NMN + 3) / 4, 256, 0, stream>>>(xm_c, pool, off_si2, dinv2, aggD, NMN);
    gemm_mfma<<<(NMN + 63) / 64, 256, 0, stream>>>(
        (const unsigned short*)aggA, WT(l, 0), (const unsigned short*)aggB, WT(l, 2),
        (const unsigned short*)aggC, WT(l, 4), (const unsigned short*)aggD, WT(l, 5),
        (const unsigned short*)xm_c, WT(l, 6), biasM + l * 128,
        (unsigned short*)xm_n, NMN);

    sage_agg_mw<<<NSN, 256, 0, stream>>>(xm_c, pool, off_ms, aggA, NSN);
    gemm_mfma<<<(NSN + 63) / 64, 256, 0, stream>>>(
        (const unsigned short*)aggA, WT(l, 1), (const unsigned short*)xs_c, WT(l, 7),
        nullptr, nullptr, nullptr, nullptr, nullptr, nullptr,
        sbl + (l * 4 + 1) * 128, (unsigned short*)xs_n, NSN);

    sage_agg_mw<<<NRN, 256, 0, stream>>>(xm_c, pool, off_mr, aggB, NRN);
    gemm_mfma<<<(NRN + 63) / 64, 256, 0, stream>>>(
        (const unsigned short*)aggB, WT(l, 3), (const unsigned short*)xr_c, WT(l, 8),
        nullptr, nullptr, nullptr, nullptr, nullptr, nullptr,
        sbl + (l * 4 + 3) * 128, (unsigned short*)xr_n, NRN);
  }

  dots_kernel<<<(LBL * 16 + 255) / 256, 256, 0, stream>>>(xs1, xm1, xr1, lbl_s, lbl_m, lbl_r, out);
}

// Round 8
// 1241.592 us; speedup vs baseline: 1.8985x; 1.3284x over previous
//
#include <hip/hip_runtime.h>
#include <hip/hip_bf16.h>

#define NSN 5000
#define NMN 100000
#define NRN 2000
#define HDIM 128
#define ESM 2000000
#define ERM 1000000
#define ESIM 2000000
#define LBL 500000

#define CNT_TOTAL (4 * NMN + NSN + NRN)  // 407000
#define POOL_TOTAL (2 * ESM + 2 * ERM + 2 * ESIM)  // 10M
#define NBTOT 1222
#define WCAP 14336   // LDS window capacity (ints) = 56 KB
#define MAXNODES 512

typedef short bf16x8 __attribute__((ext_vector_type(8)));
typedef float f32x4 __attribute__((ext_vector_type(4)));

__device__ __forceinline__ unsigned short f2bf(float f) {
  unsigned u = __float_as_uint(f);
  unsigned r = (u + 0x7fffu + ((u >> 16) & 1u)) >> 16;  // RNE
  return (unsigned short)r;
}
__device__ __forceinline__ float bf_lo(unsigned v) { return __uint_as_float(v << 16); }
__device__ __forceinline__ float bf_hi(unsigned v) { return __uint_as_float(v & 0xffff0000u); }
__device__ __forceinline__ unsigned pack2(float x, float y) {
  return (unsigned)f2bf(x) | ((unsigned)f2bf(y) << 16);
}
__device__ __forceinline__ void unpack8(uint4 v, float* f) {
  f[0] = bf_lo(v.x); f[1] = bf_hi(v.x);
  f[2] = bf_lo(v.y); f[3] = bf_hi(v.y);
  f[4] = bf_lo(v.z); f[5] = bf_hi(v.z);
  f[6] = bf_lo(v.w); f[7] = bf_hi(v.w);
}

// ---------------- CSR build ----------------

__global__ void zero_int(int* __restrict__ p, int n) {
  int i = blockIdx.x * blockDim.x + threadIdx.x;
  if (i < n) p[i] = 0;
}

// Bucket table (node-range buckets sized so pool windows fit LDS):
// sm fwd: 0..195    (NM,>>9)   sm rev: 196..508  (NS,>>4)
// rm fwd: 509..704  (NM,>>9)   rm rev: 705..829  (NR,>>4)
// si fwd: 830..1025 (NM,>>9)   si rev: 1026..1221(NM,>>9)
struct BInfo { int g; int ns; int ne; };
__device__ __forceinline__ BInfo binfo(int id) {
  BInfo bi;
  if (id < 196)       { int k = id;        bi.g = 0;                   bi.ns = k << 9; bi.ne = min(bi.ns + 512, NMN); }
  else if (id < 509)  { int k = id - 196;  bi.g = NMN;                 bi.ns = k << 4; bi.ne = min(bi.ns + 16,  NSN); }
  else if (id < 705)  { int k = id - 509;  bi.g = NMN + NSN;           bi.ns = k << 9; bi.ne = min(bi.ns + 512, NMN); }
  else if (id < 830)  { int k = id - 705;  bi.g = 2 * NMN + NSN;       bi.ns = k << 4; bi.ne = min(bi.ns + 16,  NRN); }
  else if (id < 1026) { int k = id - 830;  bi.g = 2 * NMN + NSN + NRN; bi.ns = k << 9; bi.ne = min(bi.ns + 512, NMN); }
  else                { int k = id - 1026; bi.g = 3 * NMN + NSN + NRN; bi.ns = k << 9; bi.ne = min(bi.ns + 512, NMN); }
  return bi;
}

// Per-tile LDS histogram over BUCKETS only (replaces the 12M-atomic per-node
// hist2: ~600K global atomics into a 5KB array instead -> no 122MB writeback).
template <int SHF, int NBF, int SHR, int NBR>
__global__ __launch_bounds__(256) void countbuckets(
    const int* __restrict__ a, const int* __restrict__ b, int n,
    int* __restrict__ bcnt, int bb) {
  __shared__ int hist[NBF + NBR];
  int tid = threadIdx.x;
  int base = blockIdx.x * 4096;
  for (int k = tid; k < NBF + NBR; k += 256) hist[k] = 0;
  __syncthreads();
  int end = min(base + 4096, n);
  for (int idx = base + tid; idx < end; idx += 256) {
    atomicAdd(&hist[b[idx] >> SHF], 1);
    atomicAdd(&hist[NBF + (a[idx] >> SHR)], 1);
  }
  __syncthreads();
  for (int k = tid; k < NBF + NBR; k += 256) {
    int c = hist[k];
    if (c) atomicAdd(&bcnt[bb + k], c);
  }
}

// Single-block scan of the 1222 bucket counts -> bucket starts (= staging AND
// pool layout), bcur copy for multisplit, and the off[] sentinel.
__global__ void scan_buckets(const int* __restrict__ bcnt, int* __restrict__ bstart,
                             int* __restrict__ bcur, int* __restrict__ off_sentinel) {
  __shared__ int buf[256];
  int t = threadIdx.x;
  int base = 0;
  for (int c0 = 0; c0 < NBTOT; c0 += 256) {
    int v = (c0 + t < NBTOT) ? bcnt[c0 + t] : 0;
    buf[t] = v; __syncthreads();
    for (int o = 1; o < 256; o <<= 1) {
      int a = (t >= o) ? buf[t - o] : 0;
      __syncthreads();
      buf[t] += a;
      __syncthreads();
    }
    if (c0 + t < NBTOT) {
      int excl = buf[t] - v + base;
      bstart[c0 + t] = excl;
      bcur[c0 + t] = excl;
    }
    base += buf[255];
    __syncthreads();
  }
  if (t == 0) { bstart[NBTOT] = base; *off_sentinel = base; }
}

// Phase A: multisplit edges into bucket-partitioned (target,payload) staging.
// 4096-edge tile per block; LDS hist -> one global atomic per (tile,bucket)
// -> staged pairs land in per-tile contiguous runs.
template <int SHF, int NBF, int SHR, int NBR>
__global__ __launch_bounds__(256) void multisplit(
    const int* __restrict__ a, const int* __restrict__ b, int n,
    int* __restrict__ bcur, int bb, int* __restrict__ stage) {
  __shared__ int hist[NBF + NBR];
  __shared__ int gpos[NBF + NBR];
  int tid = threadIdx.x;
  int base = blockIdx.x * 4096;
  for (int k = tid; k < NBF + NBR; k += 256) hist[k] = 0;
  __syncthreads();
  int dv[16], sv[16];
#pragma unroll
  for (int j = 0; j < 16; j++) {
    int idx = base + j * 256 + tid;
    if (idx < n) {
      sv[j] = a[idx]; dv[j] = b[idx];
      atomicAdd(&hist[dv[j] >> SHF], 1);
      atomicAdd(&hist[NBF + (sv[j] >> SHR)], 1);
    } else {
      dv[j] = -1;
    }
  }
  __syncthreads();
  for (int k = tid; k < NBF + NBR; k += 256) {
    int c = hist[k];
    gpos[k] = c ? atomicAdd(&bcur[bb + k], c) : 0;
  }
  __syncthreads();
#pragma unroll
  for (int j = 0; j < 16; j++) {
    if (dv[j] >= 0) {
      int s1 = atomicAdd(&gpos[dv[j] >> SHF], 1);
      stage[2 * s1] = dv[j]; stage[2 * s1 + 1] = sv[j];
      int s2 = atomicAdd(&gpos[NBF + (sv[j] >> SHR)], 1);
      stage[2 * s2] = sv[j]; stage[2 * s2 + 1] = dv[j];
    }
  }
}

// Phase B: one block per bucket. Derives per-node offsets itself (LDS hist of
// staged targets + LDS scan), writes the off[] range (coalesced), then does
// the private LDS-window scatter + sequential stream-out (zero write amp).
__global__ __launch_bounds__(256) void scatter_bucket(
    const int* __restrict__ stage, const int* __restrict__ bstart,
    int* __restrict__ cur, int* __restrict__ off, int* __restrict__ pool) {
  __shared__ int win[WCAP];
  __shared__ int hist[MAXNODES];
  __shared__ int part[256];
  int b = blockIdx.x;
  BInfo bi = binfo(b);
  int s0 = bstart[b], s1 = bstart[b + 1];
  int sz = s1 - s0, nn = bi.ne - bi.ns;
  int t = threadIdx.x;
  for (int k = t; k < nn; k += 256) hist[k] = 0;
  __syncthreads();
  for (int k = s0 + t; k < s1; k += 256)
    atomicAdd(&hist[stage[2 * k] - bi.ns], 1);
  __syncthreads();
  // exclusive scan over nn (<=512) entries: pair per thread
  int a0 = (2 * t < nn) ? hist[2 * t] : 0;
  int a1 = (2 * t + 1 < nn) ? hist[2 * t + 1] : 0;
  part[t] = a0 + a1;
  __syncthreads();
  for (int o = 1; o < 256; o <<= 1) {
    int a = (t >= o) ? part[t - o] : 0;
    __syncthreads();
    part[t] += a;
    __syncthreads();
  }
  int e0 = part[t] - a0 - a1;
  int e1 = e0 + a0;
  if (2 * t < nn)     { off[bi.g + bi.ns + 2 * t] = s0 + e0; hist[2 * t] = e0; }
  if (2 * t + 1 < nn) { off[bi.g + bi.ns + 2 * t + 1] = s0 + e1; hist[2 * t + 1] = e1; }
  __syncthreads();
  if (sz <= WCAP) {
    for (int k = s0 + t; k < s1; k += 256) {
      int d = stage[2 * k], s_ = stage[2 * k + 1];
      int slot = atomicAdd(&hist[d - bi.ns], 1);
      win[slot] = s_;
    }
    __syncthreads();
    for (int k = t; k < sz; k += 256) pool[s0 + k] = win[k];
  } else {
    // fallback (never expected statistically; correctness-only path)
    for (int k = s0 + t; k < s1; k += 256) {
      int d = stage[2 * k], s_ = stage[2 * k + 1];
      int slot = atomicAdd(&cur[bi.g + d], 1);
      pool[s0 + hist[d - bi.ns] + slot] = s_;
    }
  }
}

__global__ void compute_dinv(const int* __restrict__ off1, const int* __restrict__ off2,
                             float* __restrict__ dinv1, float* __restrict__ dinv2, int n) {
  int v = blockIdx.x * blockDim.x + threadIdx.x;
  if (v < n) {
    dinv1[v] = rsqrtf((float)(off1[v + 1] - off1[v] + 1));
    dinv2[v] = rsqrtf((float)(off2[v + 1] - off2[v] + 1));
  }
}

// bf16 transposed weights wt[(l*9+slot)][n][k], slots:
// 0..3 = sage_Wl rel0..3; 4,5 = gcn_W; 6 = Wr0+Wr2; 7 = Wr1; 8 = Wr3
__global__ void trans_weights(const float* __restrict__ sWl, const float* __restrict__ sWr,
                              const float* __restrict__ gW, unsigned short* __restrict__ wt) {
  int i = blockIdx.x * blockDim.x + threadIdx.x;
  if (i >= 18 * 16384) return;
  int mat = i >> 14, l = mat / 9, slot = mat % 9;
  int idx = i & 16383, nn = idx >> 7, kk = idx & 127;
  int s_ = kk * 128 + nn;  // source [k][n] row-major
  float v;
  if (slot < 4)      v = sWl[((l * 4 + slot) << 14) + s_];
  else if (slot < 6) v = gW[((l * 2 + (slot - 4)) << 14) + s_];
  else if (slot == 6) v = sWr[((l * 4 + 0) << 14) + s_] + sWr[((l * 4 + 2) << 14) + s_];
  else if (slot == 7) v = sWr[((l * 4 + 1) << 14) + s_];
  else                v = sWr[((l * 4 + 3) << 14) + s_];
  wt[i] = f2bf(v);
}

__global__ void prep_bias(const float* __restrict__ sbl, const float* __restrict__ gb,
                          float* __restrict__ biasM) {
  int i = threadIdx.x;  // 256 threads
  int l = i >> 7, j = i & 127;
  biasM[i] = sbl[(l * 4 + 0) * 128 + j] + sbl[(l * 4 + 2) * 128 + j] +
             gb[(l * 2 + 0) * 128 + j] + gb[(l * 2 + 1) * 128 + j];
}

__global__ void cast_all(const float2* __restrict__ es, const float2* __restrict__ em,
                         const float2* __restrict__ er, unsigned* __restrict__ os,
                         unsigned* __restrict__ om, unsigned* __restrict__ orr) {
  int i = blockIdx.x * blockDim.x + threadIdx.x;
  if (i < NSN * 64) { float2 v = es[i]; os[i] = pack2(v.x, v.y); }
  if (i < NMN * 64) { float2 v = em[i]; om[i] = pack2(v.x, v.y); }
  if (i < NRN * 64) { float2 v = er[i]; orr[i] = pack2(v.x, v.y); }
}

// ---------------- aggregation (quarter-wave uint4 gathers) ----------------

__global__ void sage_agg(const unsigned* __restrict__ x, const int* __restrict__ pool,
                         const int* __restrict__ off, unsigned* __restrict__ outb, int n) {
  int w = (blockIdx.x * blockDim.x + threadIdx.x) >> 6;
  if (w >= n) return;
  int lane = threadIdx.x & 63;
  int q = lane >> 4, h = lane & 15;
  int s = off[w], e = off[w + 1];
  float acc[8];
#pragma unroll
  for (int j = 0; j < 8; j++) acc[j] = 0.f;
  for (int i0 = s; i0 < e; i0 += 8) {
    int iA = i0 + q, iB = i0 + 4 + q;
    int uA = pool[min(iA, e - 1)], uB = pool[min(iB, e - 1)];
    uint4 a = *(const uint4*)(x + (size_t)uA * 64 + h * 4);
    uint4 b = *(const uint4*)(x + (size_t)uB * 64 + h * 4);
    float sA = (iA < e) ? 1.f : 0.f, sB = (iB < e) ? 1.f : 0.f;
    float fa[8], fb[8];
    unpack8(a, fa); unpack8(b, fb);
#pragma unroll
    for (int j = 0; j < 8; j++) acc[j] = fmaf(fa[j], sA, fmaf(fb[j], sB, acc[j]));
  }
#pragma unroll
  for (int j = 0; j < 8; j++) {
    acc[j] += __shfl_xor(acc[j], 16, 64);
    acc[j] += __shfl_xor(acc[j], 32, 64);
  }
  if (q == 0) {
    float inv = (e > s) ? 1.0f / (float)(e - s) : 0.0f;
    uint4 o;
    o.x = pack2(acc[0] * inv, acc[1] * inv);
    o.y = pack2(acc[2] * inv, acc[3] * inv);
    o.z = pack2(acc[4] * inv, acc[5] * inv);
    o.w = pack2(acc[6] * inv, acc[7] * inv);
    *(uint4*)(outb + (size_t)w * 64 + h * 4) = o;
  }
}

__global__ void gcn_agg(const unsigned* __restrict__ x, const int* __restrict__ pool,
                        const int* __restrict__ off, const float* __restrict__ dinv,
                        unsigned* __restrict__ outb, int n) {
  int w = (blockIdx.x * blockDim.x + threadIdx.x) >> 6;
  if (w >= n) return;
  int lane = threadIdx.x & 63;
  int q = lane >> 4, h = lane & 15;
  int s = off[w], e = off[w + 1];
  float acc[8];
#pragma unroll
  for (int j = 0; j < 8; j++) acc[j] = 0.f;
  for (int i0 = s; i0 < e; i0 += 8) {
    int iA = i0 + q, iB = i0 + 4 + q;
    int uA = pool[min(iA, e - 1)], uB = pool[min(iB, e - 1)];
    uint4 a = *(const uint4*)(x + (size_t)uA * 64 + h * 4);
    uint4 b = *(const uint4*)(x + (size_t)uB * 64 + h * 4);
    float sA = (iA < e) ? dinv[uA] : 0.f, sB = (iB < e) ? dinv[uB] : 0.f;
    float fa[8], fb[8];
    unpack8(a, fa); unpack8(b, fb);
#pragma unroll
    for (int j = 0; j < 8; j++) acc[j] = fmaf(fa[j], sA, fmaf(fb[j], sB, acc[j]));
  }
#pragma unroll
  for (int j = 0; j < 8; j++) {
    acc[j] += __shfl_xor(acc[j], 16, 64);
    acc[j] += __shfl_xor(acc[j], 32, 64);
  }
  if (q == 0) {
    float dw = dinv[w];
    uint4 xv = *(const uint4*)(x + (size_t)w * 64 + h * 4);
    float fx[8];
    unpack8(xv, fx);
    uint4 o;
    float r0 = acc[0] * dw + fx[0] * dw * dw, r1 = acc[1] * dw + fx[1] * dw * dw;
    float r2 = acc[2] * dw + fx[2] * dw * dw, r3 = acc[3] * dw + fx[3] * dw * dw;
    float r4 = acc[4] * dw + fx[4] * dw * dw, r5 = acc[5] * dw + fx[5] * dw * dw;
    float r6 = acc[6] * dw + fx[6] * dw * dw, r7 = acc[7] * dw + fx[7] * dw * dw;
    o.x = pack2(r0, r1); o.y = pack2(r2, r3); o.z = pack2(r4, r5); o.w = pack2(r6, r7);
    *(uint4*)(outb + (size_t)w * 64 + h * 4) = o;
  }
}

__global__ __launch_bounds__(256) void sage_agg_mw(const unsigned* __restrict__ x,
                                                   const int* __restrict__ pool,
                                                   const int* __restrict__ off,
                                                   unsigned* __restrict__ outb, int n) {
  __shared__ float psum[3][128];
  int node = blockIdx.x;
  if (node >= n) return;
  int sub = threadIdx.x >> 6, lane = threadIdx.x & 63;
  int q = lane >> 4, h = lane & 15;
  int s = off[node], e = off[node + 1];
  float acc[8];
#pragma unroll
  for (int j = 0; j < 8; j++) acc[j] = 0.f;
  for (int i0 = s + sub * 4; i0 < e; i0 += 16) {
    int idx = i0 + q;
    int u = pool[min(idx, e - 1)];
    uint4 a = *(const uint4*)(x + (size_t)u * 64 + h * 4);
    float sc = (idx < e) ? 1.f : 0.f;
    float fa[8];
    unpack8(a, fa);
#pragma unroll
    for (int j = 0; j < 8; j++) acc[j] = fmaf(fa[j], sc, acc[j]);
  }
#pragma unroll
  for (int j = 0; j < 8; j++) {
    acc[j] += __shfl_xor(acc[j], 16, 64);
    acc[j] += __shfl_xor(acc[j], 32, 64);
  }
  if (sub && q == 0) {
#pragma unroll
    for (int j = 0; j < 8; j++) psum[sub - 1][h * 8 + j] = acc[j];
  }
  __syncthreads();
  if (sub == 0 && q == 0) {
#pragma unroll
    for (int j = 0; j < 8; j++)
      acc[j] += psum[0][h * 8 + j] + psum[1][h * 8 + j] + psum[2][h * 8 + j];
    float inv = (e > s) ? 1.0f / (float)(e - s) : 0.0f;
    uint4 o;
    o.x = pack2(acc[0] * inv, acc[1] * inv);
    o.y = pack2(acc[2] * inv, acc[3] * inv);
    o.z = pack2(acc[4] * inv, acc[5] * inv);
    o.w = pack2(acc[6] * inv, acc[7] * inv);
    *(uint4*)(outb + (size_t)node * 64 + h * 4) = o;
  }
}

// ---------------- MFMA GEMM: out = relu(bias + sum_p A_p @ W_p) ----------------

#define LDA 136

__global__ __launch_bounds__(256) void gemm_mfma(
    const unsigned short* __restrict__ a0, const unsigned short* __restrict__ w0,
    const unsigned short* __restrict__ a1, const unsigned short* __restrict__ w1,
    const unsigned short* __restrict__ a2, const unsigned short* __restrict__ w2,
    const unsigned short* __restrict__ a3, const unsigned short* __restrict__ w3,
    const unsigned short* __restrict__ a4, const unsigned short* __restrict__ w4,
    const float* __restrict__ bias, unsigned short* __restrict__ out, int n) {
  __shared__ __align__(16) unsigned short As[64 * LDA];
  __shared__ __align__(16) unsigned short Ws[128 * LDA];

  int tid = threadIdx.x;
  int w = tid >> 6, lane = tid & 63;
  int q = lane >> 4, c = lane & 15;
  int r0 = blockIdx.x * 64;

  const unsigned short* Ap[5] = {a0, a1, a2, a3, a4};
  const unsigned short* Wp[5] = {w0, w1, w2, w3, w4};

  float bias_v[8];
#pragma unroll
  for (int n0 = 0; n0 < 8; n0++) bias_v[n0] = bias[n0 * 16 + c];

  f32x4 acc[8];
#pragma unroll
  for (int n0 = 0; n0 < 8; n0++) acc[n0] = (f32x4){0.f, 0.f, 0.f, 0.f};

  for (int p = 0; p < 5; p++) {
    if (!Ap[p]) continue;
    __syncthreads();
    for (int j = tid; j < 2048; j += 256) {
      int row = j >> 4, colc = (j & 15) * 8;
      *(uint4*)&Ws[row * LDA + colc] = *(const uint4*)(Wp[p] + row * 128 + colc);
    }
    for (int j = tid; j < 1024; j += 256) {
      int row = j >> 4, colc = (j & 15) * 8;
      uint4 v = make_uint4(0u, 0u, 0u, 0u);
      if (r0 + row < n) v = *(const uint4*)(Ap[p] + (size_t)(r0 + row) * 128 + colc);
      *(uint4*)&As[row * LDA + colc] = v;
    }
    __syncthreads();

    int arow = (w * 16 + c) * LDA;
#pragma unroll
    for (int k0 = 0; k0 < 128; k0 += 32) {
      bf16x8 af = *(const bf16x8*)&As[arow + k0 + q * 8];
#pragma unroll
      for (int n0 = 0; n0 < 8; n0++) {
        bf16x8 bfv = *(const bf16x8*)&Ws[(n0 * 16 + c) * LDA + k0 + q * 8];
        acc[n0] = __builtin_amdgcn_mfma_f32_16x16x32_bf16(af, bfv, acc[n0], 0, 0, 0);
      }
    }
  }

  __syncthreads();
#pragma unroll
  for (int n0 = 0; n0 < 8; n0++) {
#pragma unroll
    for (int reg = 0; reg < 4; reg++) {
      float v = acc[n0][reg] + bias_v[n0];
      v = fmaxf(v, 0.f);
      As[(w * 16 + q * 4 + reg) * LDA + n0 * 16 + c] = f2bf(v);
    }
  }
  __syncthreads();
  for (int j = tid; j < 1024; j += 256) {
    int row = j >> 4, colc = (j & 15) * 8;
    if (r0 + row < n)
      *(uint4*)(out + (size_t)(r0 + row) * 128 + colc) = *(const uint4*)&As[row * LDA + colc];
  }
}

// ---------------- final dot products (4 pairs per wave) ----------------

__global__ void dots_kernel(const unsigned* __restrict__ xs, const unsigned* __restrict__ xm,
                            const unsigned* __restrict__ xr, const int* __restrict__ ls,
                            const int* __restrict__ lm, const int* __restrict__ lr,
                            float* __restrict__ out) {
  int wv = (blockIdx.x * blockDim.x + threadIdx.x) >> 6;
  int lane = threadIdx.x & 63;
  int q = lane >> 4, h = lane & 15;
  int i = wv * 4 + q;
  if (i >= LBL) return;
  int im = lm[i], is = ls[i], ir = lr[i];
  uint4 mv = *(const uint4*)(xm + (size_t)im * 64 + h * 4);
  uint4 sv = *(const uint4*)(xs + (size_t)is * 64 + h * 4);
  uint4 rv = *(const uint4*)(xr + (size_t)ir * 64 + h * 4);
  float fm[8], fs[8], fr[8];
  unpack8(mv, fm); unpack8(sv, fs); unpack8(rv, fr);
  float p1 = 0.f, p2 = 0.f;
#pragma unroll
  for (int j = 0; j < 8; j++) { p1 = fmaf(fs[j], fm[j], p1); p2 = fmaf(fr[j], fm[j], p2); }
#pragma unroll
  for (int m = 1; m < 16; m <<= 1) {
    p1 += __shfl_xor(p1, m, 64);
    p2 += __shfl_xor(p2, m, 64);
  }
  if (h == 0) { out[i] = p1; out[LBL + i] = p2; }
}

// ---------------- host launcher ----------------

extern "C" void kernel_launch(void* const* d_in, const int* in_sizes, int n_in,
                              void* d_out, int out_size, void* d_ws, size_t ws_size,
                              hipStream_t stream) {
  const float* emb_s = (const float*)d_in[0];
  const float* emb_m = (const float*)d_in[1];
  const float* emb_r = (const float*)d_in[2];
  const float* sWl = (const float*)d_in[3];
  const float* sbl = (const float*)d_in[4];
  const float* sWr = (const float*)d_in[5];
  const float* gW  = (const float*)d_in[6];
  const float* gb  = (const float*)d_in[7];
  const int* src_sm  = (const int*)d_in[8];
  const int* dst_sm  = (const int*)d_in[9];
  const int* src_rm  = (const int*)d_in[10];
  const int* dst_rm  = (const int*)d_in[11];
  const int* src_sim = (const int*)d_in[12];
  const int* dst_sim = (const int*)d_in[13];
  const int* lbl_s = (const int*)d_in[14];
  const int* lbl_m = (const int*)d_in[15];
  const int* lbl_r = (const int*)d_in[16];
  float* out = (float*)d_out;

  char* p = (char*)d_ws;
  auto alloc = [&](size_t bytes) -> char* {
    char* r = p;
    p += (bytes + 255) & ~(size_t)255;
    return r;
  };

  int* cnt_base = (int*)alloc(sizeof(int) * CNT_TOTAL);  // fallback cursors only

  int* off_base = (int*)alloc(sizeof(int) * (CNT_TOTAL + 1));
  int* off_sm  = off_base;
  int* off_ms  = off_sm + NMN;
  int* off_rm  = off_ms + NSN;
  int* off_mr  = off_rm + NMN;
  int* off_si  = off_mr + NRN;
  int* off_si2 = off_si + NMN;

  int* bcnt   = (int*)alloc(sizeof(int) * 1280);
  int* bstart = (int*)alloc(sizeof(int) * 1280);
  int* bcur   = (int*)alloc(sizeof(int) * 1280);
  int* pool = (int*)alloc(sizeof(int) * POOL_TOTAL);

  float* dinv1 = (float*)alloc(sizeof(float) * NMN);
  float* dinv2 = (float*)alloc(sizeof(float) * NMN);

  unsigned* xsb = (unsigned*)alloc(sizeof(unsigned) * (size_t)NSN * 64);
  unsigned* xmb = (unsigned*)alloc(sizeof(unsigned) * (size_t)NMN * 64);
  unsigned* xrb = (unsigned*)alloc(sizeof(unsigned) * (size_t)NRN * 64);
  unsigned* xs0 = (unsigned*)alloc(sizeof(unsigned) * (size_t)NSN * 64);
  unsigned* xs1 = (unsigned*)alloc(sizeof(unsigned) * (size_t)NSN * 64);
  unsigned* xm0 = (unsigned*)alloc(sizeof(unsigned) * (size_t)NMN * 64);
  unsigned* xm1 = (unsigned*)alloc(sizeof(unsigned) * (size_t)NMN * 64);
  unsigned* xr0 = (unsigned*)alloc(sizeof(unsigned) * (size_t)NRN * 64);
  unsigned* xr1 = (unsigned*)alloc(sizeof(unsigned) * (size_t)NRN * 64);
  unsigned* aggA = (unsigned*)alloc(sizeof(unsigned) * (size_t)NMN * 64);
  unsigned* aggB = (unsigned*)alloc(sizeof(unsigned) * (size_t)NMN * 64);
  unsigned* aggC = (unsigned*)alloc(sizeof(unsigned) * (size_t)NMN * 64);
  unsigned* aggD = (unsigned*)alloc(sizeof(unsigned) * (size_t)NMN * 64);

  unsigned short* wt = (unsigned short*)alloc(sizeof(unsigned short) * 18 * 16384);
  float* biasM = (float*)alloc(sizeof(float) * 2 * 128);

  // stage aliases aggA..aggD (4 x 25.6MB contiguous = 102.4MB >= 80MB needed);
  // fill completes before any agg uses these buffers (stream-ordered).
  int* stage = (int*)aggA;

  auto WT = [&](int l, int slot) -> const unsigned short* {
    return wt + (((size_t)l * 9 + slot) << 14);
  };

  // ---- CSR build (bucket counts -> bucket scan -> multisplit -> scatter) ----
  zero_int<<<5, 256, 0, stream>>>(bcnt, 1280);
  countbuckets<9, 196, 4, 313><<<(ESM + 4095) / 4096, 256, 0, stream>>>(
      src_sm, dst_sm, ESM, bcnt, 0);
  countbuckets<9, 196, 4, 125><<<(ERM + 4095) / 4096, 256, 0, stream>>>(
      src_rm, dst_rm, ERM, bcnt, 509);
  countbuckets<9, 196, 9, 196><<<(ESIM + 4095) / 4096, 256, 0, stream>>>(
      src_sim, dst_sim, ESIM, bcnt, 830);
  scan_buckets<<<1, 256, 0, stream>>>(bcnt, bstart, bcur, off_base + CNT_TOTAL);

  multisplit<9, 196, 4, 313><<<(ESM + 4095) / 4096, 256, 0, stream>>>(
      src_sm, dst_sm, ESM, bcur, 0, stage);
  multisplit<9, 196, 4, 125><<<(ERM + 4095) / 4096, 256, 0, stream>>>(
      src_rm, dst_rm, ERM, bcur, 509, stage);
  multisplit<9, 196, 9, 196><<<(ESIM + 4095) / 4096, 256, 0, stream>>>(
      src_sim, dst_sim, ESIM, bcur, 830, stage);
  zero_int<<<(CNT_TOTAL + 255) / 256, 256, 0, stream>>>(cnt_base, CNT_TOTAL);  // fallback cursors
  scatter_bucket<<<NBTOT, 256, 0, stream>>>(stage, bstart, cnt_base, off_base, pool);

  compute_dinv<<<(NMN + 255) / 256, 256, 0, stream>>>(off_si, off_si2, dinv1, dinv2, NMN);
  trans_weights<<<(18 * 16384 + 255) / 256, 256, 0, stream>>>(sWl, sWr, gW, wt);
  prep_bias<<<1, 256, 0, stream>>>(sbl, gb, biasM);
  cast_all<<<(NMN * 64 + 255) / 256, 256, 0, stream>>>((const float2*)emb_s, (const float2*)emb_m,
                                                       (const float2*)emb_r, xsb, xmb, xrb);

  for (int l = 0; l < 2; ++l) {
    const unsigned* xs_c = l ? xs0 : xsb;
    const unsigned* xm_c = l ? xm0 : xmb;
    const unsigned* xr_c = l ? xr0 : xrb;
    unsigned* xs_n = l ? xs1 : xs0;
    unsigned* xm_n = l ? xm1 : xm0;
    unsigned* xr_n = l ? xr1 : xr0;

    sage_agg<<<(NMN + 3) / 4, 256, 0, stream>>>(xs_c, pool, off_sm, aggA, NMN);
    sage_agg<<<(NMN + 3) / 4, 256, 0, stream>>>(xr_c, pool, off_rm, aggB, NMN);
    gcn_agg<<<(NMN + 3) / 4, 256, 0, stream>>>(xm_c, pool, off_si, dinv1, aggC, NMN);
    gcn_agg<<<(NMN + 3) / 4, 256, 0, stream>>>(xm_c, pool, off_si2, dinv2, aggD, NMN);
    gemm_mfma<<<(NMN + 63) / 64, 256, 0, stream>>>(
        (const unsigned short*)aggA, WT(l, 0), (const unsigned short*)aggB, WT(l, 2),
        (const unsigned short*)aggC, WT(l, 4), (const unsigned short*)aggD, WT(l, 5),
        (const unsigned short*)xm_c, WT(l, 6), biasM + l * 128,
        (unsigned short*)xm_n, NMN);

    sage_agg_mw<<<NSN, 256, 0, stream>>>(xm_c, pool, off_ms, aggA, NSN);
    gemm_mfma<<<(NSN + 63) / 64, 256, 0, stream>>>(
        (const unsigned short*)aggA, WT(l, 1), (const unsigned short*)xs_c, WT(l, 7),
        nullptr, nullptr, nullptr, nullptr, nullptr, nullptr,
        sbl + (l * 4 + 1) * 128, (unsigned short*)xs_n, NSN);

    sage_agg_mw<<<NRN, 256, 0, stream>>>(xm_c, pool, off_mr, aggB, NRN);
    gemm_mfma<<<(NRN + 63) / 64, 256, 0, stream>>>(
        (const unsigned short*)aggB, WT(l, 3), (const unsigned short*)xr_c, WT(l, 8),
        nullptr, nullptr, nullptr, nullptr, nullptr, nullptr,
        sbl + (l * 4 + 3) * 128, (unsigned short*)xr_n, NRN);
  }

  dots_kernel<<<(LBL * 16 + 255) / 256, 256, 0, stream>>>(xs1, xm1, xr1, lbl_s, lbl_m, lbl_r, out);
}

// Round 9
// 1185.444 us; speedup vs baseline: 1.9884x; 1.0474x over previous
//
#include <hip/hip_runtime.h>
#include <hip/hip_bf16.h>

#define NSN 5000
#define NMN 100000
#define NRN 2000
#define HDIM 128
#define ESM 2000000
#define ERM 1000000
#define ESIM 2000000
#define LBL 500000

#define CNT_TOTAL (4 * NMN + NSN + NRN)  // 407000
#define POOL_TOTAL (2 * ESM + 2 * ERM + 2 * ESIM)  // 10M
#define NBTOT 1222
#define WCAP 14336   // LDS window capacity (ints) = 56 KB
#define MAXNODES 512
#define MBLK 25000   // m-node blocks in agg_all (4 nodes/block)

typedef short bf16x8 __attribute__((ext_vector_type(8)));
typedef float f32x4 __attribute__((ext_vector_type(4)));

__device__ __forceinline__ unsigned short f2bf(float f) {
  unsigned u = __float_as_uint(f);
  unsigned r = (u + 0x7fffu + ((u >> 16) & 1u)) >> 16;  // RNE
  return (unsigned short)r;
}
__device__ __forceinline__ float bf_lo(unsigned v) { return __uint_as_float(v << 16); }
__device__ __forceinline__ float bf_hi(unsigned v) { return __uint_as_float(v & 0xffff0000u); }
__device__ __forceinline__ unsigned pack2(float x, float y) {
  return (unsigned)f2bf(x) | ((unsigned)f2bf(y) << 16);
}
__device__ __forceinline__ void unpack8(uint4 v, float* f) {
  f[0] = bf_lo(v.x); f[1] = bf_hi(v.x);
  f[2] = bf_lo(v.y); f[3] = bf_hi(v.y);
  f[4] = bf_lo(v.z); f[5] = bf_hi(v.z);
  f[6] = bf_lo(v.w); f[7] = bf_hi(v.w);
}

// ---------------- CSR build ----------------

__global__ void zero_int(int* __restrict__ p, int n) {
  int i = blockIdx.x * blockDim.x + threadIdx.x;
  if (i < n) p[i] = 0;
}

// Bucket table (node-range buckets sized so pool windows fit LDS):
// sm fwd: 0..195    (NM,>>9)   sm rev: 196..508  (NS,>>4)
// rm fwd: 509..704  (NM,>>9)   rm rev: 705..829  (NR,>>4)
// si fwd: 830..1025 (NM,>>9)   si rev: 1026..1221(NM,>>9)
struct BInfo { int g; int ns; int ne; };
__device__ __forceinline__ BInfo binfo(int id) {
  BInfo bi;
  if (id < 196)       { int k = id;        bi.g = 0;                   bi.ns = k << 9; bi.ne = min(bi.ns + 512, NMN); }
  else if (id < 509)  { int k = id - 196;  bi.g = NMN;                 bi.ns = k << 4; bi.ne = min(bi.ns + 16,  NSN); }
  else if (id < 705)  { int k = id - 509;  bi.g = NMN + NSN;           bi.ns = k << 9; bi.ne = min(bi.ns + 512, NMN); }
  else if (id < 830)  { int k = id - 705;  bi.g = 2 * NMN + NSN;       bi.ns = k << 4; bi.ne = min(bi.ns + 16,  NRN); }
  else if (id < 1026) { int k = id - 830;  bi.g = 2 * NMN + NSN + NRN; bi.ns = k << 9; bi.ne = min(bi.ns + 512, NMN); }
  else                { int k = id - 1026; bi.g = 3 * NMN + NSN + NRN; bi.ns = k << 9; bi.ne = min(bi.ns + 512, NMN); }
  return bi;
}

// Per-tile LDS histogram over BUCKETS only.
template <int SHF, int NBF, int SHR, int NBR>
__global__ __launch_bounds__(256) void countbuckets(
    const int* __restrict__ a, const int* __restrict__ b, int n,
    int* __restrict__ bcnt, int bb) {
  __shared__ int hist[NBF + NBR];
  int tid = threadIdx.x;
  int base = blockIdx.x * 4096;
  for (int k = tid; k < NBF + NBR; k += 256) hist[k] = 0;
  __syncthreads();
  int end = min(base + 4096, n);
  for (int idx = base + tid; idx < end; idx += 256) {
    atomicAdd(&hist[b[idx] >> SHF], 1);
    atomicAdd(&hist[NBF + (a[idx] >> SHR)], 1);
  }
  __syncthreads();
  for (int k = tid; k < NBF + NBR; k += 256) {
    int c = hist[k];
    if (c) atomicAdd(&bcnt[bb + k], c);
  }
}

// Single-block scan of the 1222 bucket counts -> bucket starts, bcur, sentinel.
__global__ void scan_buckets(const int* __restrict__ bcnt, int* __restrict__ bstart,
                             int* __restrict__ bcur, int* __restrict__ off_sentinel) {
  __shared__ int buf[256];
  int t = threadIdx.x;
  int base = 0;
  for (int c0 = 0; c0 < NBTOT; c0 += 256) {
    int v = (c0 + t < NBTOT) ? bcnt[c0 + t] : 0;
    buf[t] = v; __syncthreads();
    for (int o = 1; o < 256; o <<= 1) {
      int a = (t >= o) ? buf[t - o] : 0;
      __syncthreads();
      buf[t] += a;
      __syncthreads();
    }
    if (c0 + t < NBTOT) {
      int excl = buf[t] - v + base;
      bstart[c0 + t] = excl;
      bcur[c0 + t] = excl;
    }
    base += buf[255];
    __syncthreads();
  }
  if (t == 0) { bstart[NBTOT] = base; *off_sentinel = base; }
}

// Phase A: multisplit edges into bucket-partitioned (target,payload) int2 staging.
template <int SHF, int NBF, int SHR, int NBR>
__global__ __launch_bounds__(256) void multisplit(
    const int* __restrict__ a, const int* __restrict__ b, int n,
    int* __restrict__ bcur, int bb, int2* __restrict__ stage) {
  __shared__ int hist[NBF + NBR];
  __shared__ int gpos[NBF + NBR];
  int tid = threadIdx.x;
  int base = blockIdx.x * 4096;
  for (int k = tid; k < NBF + NBR; k += 256) hist[k] = 0;
  __syncthreads();
  int dv[16], sv[16];
#pragma unroll
  for (int j = 0; j < 16; j++) {
    int idx = base + j * 256 + tid;
    if (idx < n) {
      sv[j] = a[idx]; dv[j] = b[idx];
      atomicAdd(&hist[dv[j] >> SHF], 1);
      atomicAdd(&hist[NBF + (sv[j] >> SHR)], 1);
    } else {
      dv[j] = -1;
    }
  }
  __syncthreads();
  for (int k = tid; k < NBF + NBR; k += 256) {
    int c = hist[k];
    gpos[k] = c ? atomicAdd(&bcur[bb + k], c) : 0;
  }
  __syncthreads();
#pragma unroll
  for (int j = 0; j < 16; j++) {
    if (dv[j] >= 0) {
      int s1 = atomicAdd(&gpos[dv[j] >> SHF], 1);
      stage[s1] = make_int2(dv[j], sv[j]);
      int s2 = atomicAdd(&gpos[NBF + (sv[j] >> SHR)], 1);
      stage[s2] = make_int2(sv[j], dv[j]);
    }
  }
}

// Phase B: one block per bucket. Derives per-node offsets (LDS hist + scan),
// writes off[] coalesced, then LDS-window scatter + sequential stream-out.
__global__ __launch_bounds__(256) void scatter_bucket(
    const int2* __restrict__ stage, const int* __restrict__ bstart,
    int* __restrict__ cur, int* __restrict__ off, int* __restrict__ pool) {
  __shared__ int win[WCAP];
  __shared__ int hist[MAXNODES];
  __shared__ int part[256];
  int b = blockIdx.x;
  BInfo bi = binfo(b);
  int s0 = bstart[b], s1 = bstart[b + 1];
  int sz = s1 - s0, nn = bi.ne - bi.ns;
  int t = threadIdx.x;
  for (int k = t; k < nn; k += 256) hist[k] = 0;
  __syncthreads();
  for (int k = s0 + t; k < s1; k += 256)
    atomicAdd(&hist[stage[k].x - bi.ns], 1);
  __syncthreads();
  int a0 = (2 * t < nn) ? hist[2 * t] : 0;
  int a1 = (2 * t + 1 < nn) ? hist[2 * t + 1] : 0;
  part[t] = a0 + a1;
  __syncthreads();
  for (int o = 1; o < 256; o <<= 1) {
    int a = (t >= o) ? part[t - o] : 0;
    __syncthreads();
    part[t] += a;
    __syncthreads();
  }
  int e0 = part[t] - a0 - a1;
  int e1 = e0 + a0;
  if (2 * t < nn)     { off[bi.g + bi.ns + 2 * t] = s0 + e0; hist[2 * t] = e0; }
  if (2 * t + 1 < nn) { off[bi.g + bi.ns + 2 * t + 1] = s0 + e1; hist[2 * t + 1] = e1; }
  __syncthreads();
  if (sz <= WCAP) {
    for (int k = s0 + t; k < s1; k += 256) {
      int2 pr = stage[k];
      int slot = atomicAdd(&hist[pr.x - bi.ns], 1);
      win[slot] = pr.y;
    }
    __syncthreads();
    for (int k = t; k < sz; k += 256) pool[s0 + k] = win[k];
  } else {
    // fallback (never expected statistically; correctness-only path)
    for (int k = s0 + t; k < s1; k += 256) {
      int2 pr = stage[k];
      int slot = atomicAdd(&cur[bi.g + pr.x], 1);
      pool[s0 + hist[pr.x - bi.ns] + slot] = pr.y;
    }
  }
}

__global__ void compute_dinv(const int* __restrict__ off1, const int* __restrict__ off2,
                             float* __restrict__ dinv1, float* __restrict__ dinv2, int n) {
  int v = blockIdx.x * blockDim.x + threadIdx.x;
  if (v < n) {
    dinv1[v] = rsqrtf((float)(off1[v + 1] - off1[v] + 1));
    dinv2[v] = rsqrtf((float)(off2[v + 1] - off2[v] + 1));
  }
}

// bf16 transposed weights wt[(l*9+slot)][n][k], slots:
// 0..3 = sage_Wl rel0..3; 4,5 = gcn_W; 6 = Wr0+Wr2; 7 = Wr1; 8 = Wr3
__global__ void trans_weights(const float* __restrict__ sWl, const float* __restrict__ sWr,
                              const float* __restrict__ gW, unsigned short* __restrict__ wt) {
  int i = blockIdx.x * blockDim.x + threadIdx.x;
  if (i >= 18 * 16384) return;
  int mat = i >> 14, l = mat / 9, slot = mat % 9;
  int idx = i & 16383, nn = idx >> 7, kk = idx & 127;
  int s_ = kk * 128 + nn;  // source [k][n] row-major
  float v;
  if (slot < 4)      v = sWl[((l * 4 + slot) << 14) + s_];
  else if (slot < 6) v = gW[((l * 2 + (slot - 4)) << 14) + s_];
  else if (slot == 6) v = sWr[((l * 4 + 0) << 14) + s_] + sWr[((l * 4 + 2) << 14) + s_];
  else if (slot == 7) v = sWr[((l * 4 + 1) << 14) + s_];
  else                v = sWr[((l * 4 + 3) << 14) + s_];
  wt[i] = f2bf(v);
}

__global__ void prep_bias(const float* __restrict__ sbl, const float* __restrict__ gb,
                          float* __restrict__ biasM) {
  int i = threadIdx.x;  // 256 threads
  int l = i >> 7, j = i & 127;
  biasM[i] = sbl[(l * 4 + 0) * 128 + j] + sbl[(l * 4 + 2) * 128 + j] +
             gb[(l * 2 + 0) * 128 + j] + gb[(l * 2 + 1) * 128 + j];
}

__global__ void cast_all(const float2* __restrict__ es, const float2* __restrict__ em,
                         const float2* __restrict__ er, unsigned* __restrict__ os,
                         unsigned* __restrict__ om, unsigned* __restrict__ orr) {
  int i = blockIdx.x * blockDim.x + threadIdx.x;
  if (i < NSN * 64) { float2 v = es[i]; os[i] = pack2(v.x, v.y); }
  if (i < NMN * 64) { float2 v = em[i]; om[i] = pack2(v.x, v.y); }
  if (i < NRN * 64) { float2 v = er[i]; orr[i] = pack2(v.x, v.y); }
}

// ---------------- fused layer aggregation ----------------
// ONE dispatch does all 6 aggregations of a layer, so each XCD streams the
// 25.6MB xm table ~once (R8 showed each separate xm-gather dispatch pays the
// full 8x25.6MB per-XCD stream: 4 dispatches = 4x the compulsory traffic).
// Blocks 0..MBLK-1: 4 m-nodes/block (1 wave each) -> aggA,B,C,D.
// Blocks MBLK..MBLK+NSN-1: s-node, 4-wave, ms list -> aggS.
// Blocks MBLK+NSN..: r-node, 4-wave, mr list -> aggR.

__device__ __forceinline__ void gsum_plain(const unsigned* __restrict__ x,
                                           const int* __restrict__ pool, int s, int e,
                                           int q, int h, float* acc) {
  for (int i0 = s; i0 < e; i0 += 8) {
    int iA = i0 + q, iB = i0 + 4 + q;
    int uA = pool[min(iA, e - 1)], uB = pool[min(iB, e - 1)];
    uint4 a = *(const uint4*)(x + (size_t)uA * 64 + h * 4);
    uint4 b = *(const uint4*)(x + (size_t)uB * 64 + h * 4);
    float sA = (iA < e) ? 1.f : 0.f, sB = (iB < e) ? 1.f : 0.f;
    float fa[8], fb[8];
    unpack8(a, fa); unpack8(b, fb);
#pragma unroll
    for (int j = 0; j < 8; j++) acc[j] = fmaf(fa[j], sA, fmaf(fb[j], sB, acc[j]));
  }
}

__device__ __forceinline__ void gsum_gcn(const unsigned* __restrict__ x,
                                         const int* __restrict__ pool,
                                         const float* __restrict__ dinv, int s, int e,
                                         int q, int h, float* acc) {
  for (int i0 = s; i0 < e; i0 += 8) {
    int iA = i0 + q, iB = i0 + 4 + q;
    int uA = pool[min(iA, e - 1)], uB = pool[min(iB, e - 1)];
    uint4 a = *(const uint4*)(x + (size_t)uA * 64 + h * 4);
    uint4 b = *(const uint4*)(x + (size_t)uB * 64 + h * 4);
    float sA = (iA < e) ? dinv[uA] : 0.f, sB = (iB < e) ? dinv[uB] : 0.f;
    float fa[8], fb[8];
    unpack8(a, fa); unpack8(b, fb);
#pragma unroll
    for (int j = 0; j < 8; j++) acc[j] = fmaf(fa[j], sA, fmaf(fb[j], sB, acc[j]));
  }
}

__device__ __forceinline__ void wave_reduce(float* acc) {
#pragma unroll
  for (int j = 0; j < 8; j++) {
    acc[j] += __shfl_xor(acc[j], 16, 64);
    acc[j] += __shfl_xor(acc[j], 32, 64);
  }
}

__global__ __launch_bounds__(256) void agg_all(
    const unsigned* __restrict__ xs, const unsigned* __restrict__ xm,
    const unsigned* __restrict__ xr, const int* __restrict__ pool,
    const int* __restrict__ off_sm, const int* __restrict__ off_rm,
    const int* __restrict__ off_si, const int* __restrict__ off_si2,
    const int* __restrict__ off_ms, const int* __restrict__ off_mr,
    const float* __restrict__ dinv1, const float* __restrict__ dinv2,
    unsigned* __restrict__ aggA, unsigned* __restrict__ aggB,
    unsigned* __restrict__ aggC, unsigned* __restrict__ aggD,
    unsigned* __restrict__ aggS, unsigned* __restrict__ aggR) {
  __shared__ float psum[3][128];
  int b = blockIdx.x;
  int lane = threadIdx.x & 63;
  int q = lane >> 4, h = lane & 15;

  if (b < MBLK) {
    int w = b * 4 + (threadIdx.x >> 6);
    if (w >= NMN) return;
    float acc[8];
    // aggA: mean over sm-fwd, from xs
    {
      int s = off_sm[w], e = off_sm[w + 1];
#pragma unroll
      for (int j = 0; j < 8; j++) acc[j] = 0.f;
      gsum_plain(xs, pool, s, e, q, h, acc);
      wave_reduce(acc);
      if (q == 0) {
        float inv = (e > s) ? 1.0f / (float)(e - s) : 0.0f;
        uint4 o;
        o.x = pack2(acc[0] * inv, acc[1] * inv);
        o.y = pack2(acc[2] * inv, acc[3] * inv);
        o.z = pack2(acc[4] * inv, acc[5] * inv);
        o.w = pack2(acc[6] * inv, acc[7] * inv);
        *(uint4*)(aggA + (size_t)w * 64 + h * 4) = o;
      }
    }
    // aggB: mean over rm-fwd, from xr
    {
      int s = off_rm[w], e = off_rm[w + 1];
#pragma unroll
      for (int j = 0; j < 8; j++) acc[j] = 0.f;
      gsum_plain(xr, pool, s, e, q, h, acc);
      wave_reduce(acc);
      if (q == 0) {
        float inv = (e > s) ? 1.0f / (float)(e - s) : 0.0f;
        uint4 o;
        o.x = pack2(acc[0] * inv, acc[1] * inv);
        o.y = pack2(acc[2] * inv, acc[3] * inv);
        o.z = pack2(acc[4] * inv, acc[5] * inv);
        o.w = pack2(acc[6] * inv, acc[7] * inv);
        *(uint4*)(aggB + (size_t)w * 64 + h * 4) = o;
      }
    }
    // aggC: gcn over si-fwd (dinv1), from xm
    {
      int s = off_si[w], e = off_si[w + 1];
#pragma unroll
      for (int j = 0; j < 8; j++) acc[j] = 0.f;
      gsum_gcn(xm, pool, dinv1, s, e, q, h, acc);
      wave_reduce(acc);
      if (q == 0) {
        float dw = dinv1[w];
        uint4 xv = *(const uint4*)(xm + (size_t)w * 64 + h * 4);
        float fx[8];
        unpack8(xv, fx);
        uint4 o;
        o.x = pack2(acc[0] * dw + fx[0] * dw * dw, acc[1] * dw + fx[1] * dw * dw);
        o.y = pack2(acc[2] * dw + fx[2] * dw * dw, acc[3] * dw + fx[3] * dw * dw);
        o.z = pack2(acc[4] * dw + fx[4] * dw * dw, acc[5] * dw + fx[5] * dw * dw);
        o.w = pack2(acc[6] * dw + fx[6] * dw * dw, acc[7] * dw + fx[7] * dw * dw);
        *(uint4*)(aggC + (size_t)w * 64 + h * 4) = o;
      }
    }
    // aggD: gcn over si-rev (dinv2), from xm
    {
      int s = off_si2[w], e = off_si2[w + 1];
#pragma unroll
      for (int j = 0; j < 8; j++) acc[j] = 0.f;
      gsum_gcn(xm, pool, dinv2, s, e, q, h, acc);
      wave_reduce(acc);
      if (q == 0) {
        float dw = dinv2[w];
        uint4 xv = *(const uint4*)(xm + (size_t)w * 64 + h * 4);
        float fx[8];
        unpack8(xv, fx);
        uint4 o;
        o.x = pack2(acc[0] * dw + fx[0] * dw * dw, acc[1] * dw + fx[1] * dw * dw);
        o.y = pack2(acc[2] * dw + fx[2] * dw * dw, acc[3] * dw + fx[3] * dw * dw);
        o.z = pack2(acc[4] * dw + fx[4] * dw * dw, acc[5] * dw + fx[5] * dw * dw);
        o.w = pack2(acc[6] * dw + fx[6] * dw * dw, acc[7] * dw + fx[7] * dw * dw);
        *(uint4*)(aggD + (size_t)w * 64 + h * 4) = o;
      }
    }
  } else {
    // s/r multiwave path (mean over ms/mr lists, from xm)
    int node;
    const int* offp;
    unsigned* outb;
    if (b < MBLK + NSN) { node = b - MBLK; offp = off_ms; outb = aggS; }
    else                { node = b - MBLK - NSN; offp = off_mr; outb = aggR; }
    int sub = threadIdx.x >> 6;
    int s = offp[node], e = offp[node + 1];
    float acc[8];
#pragma unroll
    for (int j = 0; j < 8; j++) acc[j] = 0.f;
    for (int i0 = s + sub * 4; i0 < e; i0 += 16) {
      int idx = i0 + q;
      int u = pool[min(idx, e - 1)];
      uint4 a = *(const uint4*)(xm + (size_t)u * 64 + h * 4);
      float sc = (idx < e) ? 1.f : 0.f;
      float fa[8];
      unpack8(a, fa);
#pragma unroll
      for (int j = 0; j < 8; j++) acc[j] = fmaf(fa[j], sc, acc[j]);
    }
    wave_reduce(acc);
    if (sub && q == 0) {
#pragma unroll
      for (int j = 0; j < 8; j++) psum[sub - 1][h * 8 + j] = acc[j];
    }
    __syncthreads();
    if (sub == 0 && q == 0) {
#pragma unroll
      for (int j = 0; j < 8; j++)
        acc[j] += psum[0][h * 8 + j] + psum[1][h * 8 + j] + psum[2][h * 8 + j];
      float inv = (e > s) ? 1.0f / (float)(e - s) : 0.0f;
      uint4 o;
      o.x = pack2(acc[0] * inv, acc[1] * inv);
      o.y = pack2(acc[2] * inv, acc[3] * inv);
      o.z = pack2(acc[4] * inv, acc[5] * inv);
      o.w = pack2(acc[6] * inv, acc[7] * inv);
      *(uint4*)(outb + (size_t)node * 64 + h * 4) = o;
    }
  }
}

// ---------------- MFMA GEMM: out = relu(bias + sum_p A_p @ W_p) ----------------

#define LDA 136

__global__ __launch_bounds__(256) void gemm_mfma(
    const unsigned short* __restrict__ a0, const unsigned short* __restrict__ w0,
    const unsigned short* __restrict__ a1, const unsigned short* __restrict__ w1,
    const unsigned short* __restrict__ a2, const unsigned short* __restrict__ w2,
    const unsigned short* __restrict__ a3, const unsigned short* __restrict__ w3,
    const unsigned short* __restrict__ a4, const unsigned short* __restrict__ w4,
    const float* __restrict__ bias, unsigned short* __restrict__ out, int n) {
  __shared__ __align__(16) unsigned short As[64 * LDA];
  __shared__ __align__(16) unsigned short Ws[128 * LDA];

  int tid = threadIdx.x;
  int w = tid >> 6, lane = tid & 63;
  int q = lane >> 4, c = lane & 15;
  int r0 = blockIdx.x * 64;

  const unsigned short* Ap[5] = {a0, a1, a2, a3, a4};
  const unsigned short* Wp[5] = {w0, w1, w2, w3, w4};

  float bias_v[8];
#pragma unroll
  for (int n0 = 0; n0 < 8; n0++) bias_v[n0] = bias[n0 * 16 + c];

  f32x4 acc[8];
#pragma unroll
  for (int n0 = 0; n0 < 8; n0++) acc[n0] = (f32x4){0.f, 0.f, 0.f, 0.f};

  for (int p = 0; p < 5; p++) {
    if (!Ap[p]) continue;
    __syncthreads();
    for (int j = tid; j < 2048; j += 256) {
      int row = j >> 4, colc = (j & 15) * 8;
      *(uint4*)&Ws[row * LDA + colc] = *(const uint4*)(Wp[p] + row * 128 + colc);
    }
    for (int j = tid; j < 1024; j += 256) {
      int row = j >> 4, colc = (j & 15) * 8;
      uint4 v = make_uint4(0u, 0u, 0u, 0u);
      if (r0 + row < n) v = *(const uint4*)(Ap[p] + (size_t)(r0 + row) * 128 + colc);
      *(uint4*)&As[row * LDA + colc] = v;
    }
    __syncthreads();

    int arow = (w * 16 + c) * LDA;
#pragma unroll
    for (int k0 = 0; k0 < 128; k0 += 32) {
      bf16x8 af = *(const bf16x8*)&As[arow + k0 + q * 8];
#pragma unroll
      for (int n0 = 0; n0 < 8; n0++) {
        bf16x8 bfv = *(const bf16x8*)&Ws[(n0 * 16 + c) * LDA + k0 + q * 8];
        acc[n0] = __builtin_amdgcn_mfma_f32_16x16x32_bf16(af, bfv, acc[n0], 0, 0, 0);
      }
    }
  }

  __syncthreads();
#pragma unroll
  for (int n0 = 0; n0 < 8; n0++) {
#pragma unroll
    for (int reg = 0; reg < 4; reg++) {
      float v = acc[n0][reg] + bias_v[n0];
      v = fmaxf(v, 0.f);
      As[(w * 16 + q * 4 + reg) * LDA + n0 * 16 + c] = f2bf(v);
    }
  }
  __syncthreads();
  for (int j = tid; j < 1024; j += 256) {
    int row = j >> 4, colc = (j & 15) * 8;
    if (r0 + row < n)
      *(uint4*)(out + (size_t)(r0 + row) * 128 + colc) = *(const uint4*)&As[row * LDA + colc];
  }
}

// ---------------- final dot products (4 pairs per wave) ----------------

__global__ void dots_kernel(const unsigned* __restrict__ xs, const unsigned* __restrict__ xm,
                            const unsigned* __restrict__ xr, const int* __restrict__ ls,
                            const int* __restrict__ lm, const int* __restrict__ lr,
                            float* __restrict__ out) {
  int wv = (blockIdx.x * blockDim.x + threadIdx.x) >> 6;
  int lane = threadIdx.x & 63;
  int q = lane >> 4, h = lane & 15;
  int i = wv * 4 + q;
  if (i >= LBL) return;
  int im = lm[i], is = ls[i], ir = lr[i];
  uint4 mv = *(const uint4*)(xm + (size_t)im * 64 + h * 4);
  uint4 sv = *(const uint4*)(xs + (size_t)is * 64 + h * 4);
  uint4 rv = *(const uint4*)(xr + (size_t)ir * 64 + h * 4);
  float fm[8], fs[8], fr[8];
  unpack8(mv, fm); unpack8(sv, fs); unpack8(rv, fr);
  float p1 = 0.f, p2 = 0.f;
#pragma unroll
  for (int j = 0; j < 8; j++) { p1 = fmaf(fs[j], fm[j], p1); p2 = fmaf(fr[j], fm[j], p2); }
#pragma unroll
  for (int m = 1; m < 16; m <<= 1) {
    p1 += __shfl_xor(p1, m, 64);
    p2 += __shfl_xor(p2, m, 64);
  }
  if (h == 0) { out[i] = p1; out[LBL + i] = p2; }
}

// ---------------- host launcher ----------------

extern "C" void kernel_launch(void* const* d_in, const int* in_sizes, int n_in,
                              void* d_out, int out_size, void* d_ws, size_t ws_size,
                              hipStream_t stream) {
  const float* emb_s = (const float*)d_in[0];
  const float* emb_m = (const float*)d_in[1];
  const float* emb_r = (const float*)d_in[2];
  const float* sWl = (const float*)d_in[3];
  const float* sbl = (const float*)d_in[4];
  const float* sWr = (const float*)d_in[5];
  const float* gW  = (const float*)d_in[6];
  const float* gb  = (const float*)d_in[7];
  const int* src_sm  = (const int*)d_in[8];
  const int* dst_sm  = (const int*)d_in[9];
  const int* src_rm  = (const int*)d_in[10];
  const int* dst_rm  = (const int*)d_in[11];
  const int* src_sim = (const int*)d_in[12];
  const int* dst_sim = (const int*)d_in[13];
  const int* lbl_s = (const int*)d_in[14];
  const int* lbl_m = (const int*)d_in[15];
  const int* lbl_r = (const int*)d_in[16];
  float* out = (float*)d_out;

  char* p = (char*)d_ws;
  auto alloc = [&](size_t bytes) -> char* {
    char* r = p;
    p += (bytes + 255) & ~(size_t)255;
    return r;
  };

  int* cnt_base = (int*)alloc(sizeof(int) * CNT_TOTAL);  // fallback cursors only

  int* off_base = (int*)alloc(sizeof(int) * (CNT_TOTAL + 1));
  int* off_sm  = off_base;
  int* off_ms  = off_sm + NMN;
  int* off_rm  = off_ms + NSN;
  int* off_mr  = off_rm + NMN;
  int* off_si  = off_mr + NRN;
  int* off_si2 = off_si + NMN;

  int* bcnt   = (int*)alloc(sizeof(int) * 1280);
  int* bstart = (int*)alloc(sizeof(int) * 1280);
  int* bcur   = (int*)alloc(sizeof(int) * 1280);
  int* pool = (int*)alloc(sizeof(int) * POOL_TOTAL);

  float* dinv1 = (float*)alloc(sizeof(float) * NMN);
  float* dinv2 = (float*)alloc(sizeof(float) * NMN);

  unsigned* xsb = (unsigned*)alloc(sizeof(unsigned) * (size_t)NSN * 64);
  unsigned* xmb = (unsigned*)alloc(sizeof(unsigned) * (size_t)NMN * 64);
  unsigned* xrb = (unsigned*)alloc(sizeof(unsigned) * (size_t)NRN * 64);
  unsigned* xs0 = (unsigned*)alloc(sizeof(unsigned) * (size_t)NSN * 64);
  unsigned* xs1 = (unsigned*)alloc(sizeof(unsigned) * (size_t)NSN * 64);
  unsigned* xm0 = (unsigned*)alloc(sizeof(unsigned) * (size_t)NMN * 64);
  unsigned* xm1 = (unsigned*)alloc(sizeof(unsigned) * (size_t)NMN * 64);
  unsigned* xr0 = (unsigned*)alloc(sizeof(unsigned) * (size_t)NRN * 64);
  unsigned* xr1 = (unsigned*)alloc(sizeof(unsigned) * (size_t)NRN * 64);
  unsigned* aggA = (unsigned*)alloc(sizeof(unsigned) * (size_t)NMN * 64);
  unsigned* aggB = (unsigned*)alloc(sizeof(unsigned) * (size_t)NMN * 64);
  unsigned* aggC = (unsigned*)alloc(sizeof(unsigned) * (size_t)NMN * 64);
  unsigned* aggD = (unsigned*)alloc(sizeof(unsigned) * (size_t)NMN * 64);
  unsigned* aggS = (unsigned*)alloc(sizeof(unsigned) * (size_t)NSN * 64);
  unsigned* aggR = (unsigned*)alloc(sizeof(unsigned) * (size_t)NRN * 64);

  unsigned short* wt = (unsigned short*)alloc(sizeof(unsigned short) * 18 * 16384);
  float* biasM = (float*)alloc(sizeof(float) * 2 * 128);

  // stage aliases aggA..aggD (4 x 25.6MB contiguous = 102.4MB >= 80MB needed);
  // fill completes before any agg uses these buffers (stream-ordered).
  int2* stage = (int2*)aggA;

  auto WT = [&](int l, int slot) -> const unsigned short* {
    return wt + (((size_t)l * 9 + slot) << 14);
  };

  // ---- CSR build (bucket counts -> bucket scan -> multisplit -> scatter) ----
  zero_int<<<5, 256, 0, stream>>>(bcnt, 1280);
  countbuckets<9, 196, 4, 313><<<(ESM + 4095) / 4096, 256, 0, stream>>>(
      src_sm, dst_sm, ESM, bcnt, 0);
  countbuckets<9, 196, 4, 125><<<(ERM + 4095) / 4096, 256, 0, stream>>>(
      src_rm, dst_rm, ERM, bcnt, 509);
  countbuckets<9, 196, 9, 196><<<(ESIM + 4095) / 4096, 256, 0, stream>>>(
      src_sim, dst_sim, ESIM, bcnt, 830);
  scan_buckets<<<1, 256, 0, stream>>>(bcnt, bstart, bcur, off_base + CNT_TOTAL);

  multisplit<9, 196, 4, 313><<<(ESM + 4095) / 4096, 256, 0, stream>>>(
      src_sm, dst_sm, ESM, bcur, 0, stage);
  multisplit<9, 196, 4, 125><<<(ERM + 4095) / 4096, 256, 0, stream>>>(
      src_rm, dst_rm, ERM, bcur, 509, stage);
  multisplit<9, 196, 9, 196><<<(ESIM + 4095) / 4096, 256, 0, stream>>>(
      src_sim, dst_sim, ESIM, bcur, 830, stage);
  zero_int<<<(CNT_TOTAL + 255) / 256, 256, 0, stream>>>(cnt_base, CNT_TOTAL);  // fallback cursors
  scatter_bucket<<<NBTOT, 256, 0, stream>>>(stage, bstart, cnt_base, off_base, pool);

  compute_dinv<<<(NMN + 255) / 256, 256, 0, stream>>>(off_si, off_si2, dinv1, dinv2, NMN);
  trans_weights<<<(18 * 16384 + 255) / 256, 256, 0, stream>>>(sWl, sWr, gW, wt);
  prep_bias<<<1, 256, 0, stream>>>(sbl, gb, biasM);
  cast_all<<<(NMN * 64 + 255) / 256, 256, 0, stream>>>((const float2*)emb_s, (const float2*)emb_m,
                                                       (const float2*)emb_r, xsb, xmb, xrb);

  const int AGG_GRID = MBLK + NSN + NRN;  // 32000
  for (int l = 0; l < 2; ++l) {
    const unsigned* xs_c = l ? xs0 : xsb;
    const unsigned* xm_c = l ? xm0 : xmb;
    const unsigned* xr_c = l ? xr0 : xrb;
    unsigned* xs_n = l ? xs1 : xs0;
    unsigned* xm_n = l ? xm1 : xm0;
    unsigned* xr_n = l ? xr1 : xr0;

    agg_all<<<AGG_GRID, 256, 0, stream>>>(
        xs_c, xm_c, xr_c, pool, off_sm, off_rm, off_si, off_si2, off_ms, off_mr,
        dinv1, dinv2, aggA, aggB, aggC, aggD, aggS, aggR);

    gemm_mfma<<<(NMN + 63) / 64, 256, 0, stream>>>(
        (const unsigned short*)aggA, WT(l, 0), (const unsigned short*)aggB, WT(l, 2),
        (const unsigned short*)aggC, WT(l, 4), (const unsigned short*)aggD, WT(l, 5),
        (const unsigned short*)xm_c, WT(l, 6), biasM + l * 128,
        (unsigned short*)xm_n, NMN);
    gemm_mfma<<<(NSN + 63) / 64, 256, 0, stream>>>(
        (const unsigned short*)aggS, WT(l, 1), (const unsigned short*)xs_c, WT(l, 7),
        nullptr, nullptr, nullptr, nullptr, nullptr, nullptr,
        sbl + (l * 4 + 1) * 128, (unsigned short*)xs_n, NSN);
    gemm_mfma<<<(NRN + 63) / 64, 256, 0, stream>>>(
        (const unsigned short*)aggR, WT(l, 3), (const unsigned short*)xr_c, WT(l, 8),
        nullptr, nullptr, nullptr, nullptr, nullptr, nullptr,
        sbl + (l * 4 + 3) * 128, (unsigned short*)xr_n, NRN);
  }

  dots_kernel<<<(LBL * 16 + 255) / 256, 256, 0, stream>>>(xs1, xm1, xr1, lbl_s, lbl_m, lbl_r, out);
}